// Round 8
// baseline (391.840 us; speedup 1.0000x reference)
//
#include <hip/hip_runtime.h>

#define NNODES 50000
#define DIM 512
#define HID 128
#define NCLS 32
#define NBINS 196          // ceil(50000 / 256), bin = dst >> 8
#define CHUNK 4096         // edges per block in hist/scatter passes
#define PB 4               // slices per bin in count/place passes
#define AGG_WAVES_G1 4096
#define AGG_WAVES_G2 8192
#define A3_WAVES 8192
#define HS_SCALE 64.0f
#define HS_ISCALE 0.015625f

typedef __attribute__((ext_vector_type(8))) short bf16x8;
typedef __attribute__((ext_vector_type(4))) float f32x4;
typedef __attribute__((ext_vector_type(2))) float f32x2;

__device__ __forceinline__ unsigned short f2bf(float f) {
    union { float f; unsigned int u; } a; a.f = f;
    unsigned int u = a.u;
    u += 0x7fff + ((u >> 16) & 1);   // round-to-nearest-even
    return (unsigned short)(u >> 16);
}
__device__ __forceinline__ float bf2f(unsigned short h) {
    union { unsigned int u; float f; } a; a.u = ((unsigned int)h) << 16;
    return a.f;
}
// f32 -> fp8 e4m3 (OCP on gfx950), RNE
__device__ __forceinline__ unsigned char f2fp8(float f) {
    int p = __builtin_amdgcn_cvt_pk_fp8_f32(f, 0.f, 0, false);
    return (unsigned char)(p & 0xff);
}
// 4 packed fp8 -> two f32x2 accumulators (v_pk_add_f32)
__device__ __forceinline__ void fp8add2(unsigned int u, f32x2& a01, f32x2& a23) {
    a01 += __builtin_amdgcn_cvt_pk_f32_fp8((int)u, false);
    a23 += __builtin_amdgcn_cvt_pk_f32_fp8((int)u, true);
}
// min v in [0,NNODES] with rp[v] >= q
__device__ __forceinline__ int lbound(const int* __restrict__ rp, int q) {
    int lo = 0, hi = NNODES;
    while (lo < hi) { int mid = (lo + hi) >> 1; if (rp[mid] >= q) hi = mid; else lo = mid + 1; }
    return lo;
}
// in-place exclusive scan of row[0..n), block of 256; row sum -> *total
__device__ __forceinline__ void scan_inplace(int* __restrict__ row, int n, int* __restrict__ total) {
    __shared__ int wsum[4];
    int tid = threadIdx.x, lane = tid & 63, wid = tid >> 6;
    int base = 0;
    for (int start = 0; start < n; start += 256) {
        int i = start + tid;
        int v = (i < n) ? row[i] : 0;
        int x = v;
        #pragma unroll
        for (int off = 1; off < 64; off <<= 1) {
            int t = __shfl_up(x, off);
            if (lane >= off) x += t;
        }
        if (lane == 63) wsum[wid] = x;
        __syncthreads();
        int woff = 0, tot = 0;
        #pragma unroll
        for (int w = 0; w < 4; ++w) { int s = wsum[w]; if (w < wid) woff += s; tot += s; }
        __syncthreads();
        if (i < n) row[i] = base + woff + x - v;
        base += tot;
    }
    if (tid == 0) *total = base;
}

// ============ deterministic-sum CSR build: counting sort by dst ============

__global__ __launch_bounds__(256)
void hist2_kernel(const int* __restrict__ dst1, int E1, int nb1, int* __restrict__ hist1,
                  const int* __restrict__ dst2, int E2, int nb2, int* __restrict__ hist2) {
    __shared__ int h[NBINS];
    int blk = blockIdx.x;
    const int* dst; int E, nb, b; int* hist;
    if (blk < nb1) { dst = dst1; E = E1; nb = nb1; b = blk; hist = hist1; }
    else { dst = dst2; E = E2; nb = nb2; b = blk - nb1; hist = hist2; }
    int tid = threadIdx.x;
    for (int i = tid; i < NBINS; i += 256) h[i] = 0;
    __syncthreads();
    int e0 = b * CHUNK;
    int e1 = min(E, e0 + CHUNK);
    for (int e = e0 + tid; e < e1; e += 256)
        atomicAdd(&h[dst[e] >> 8], 1);
    __syncthreads();
    for (int i = tid; i < NBINS; i += 256)
        hist[(size_t)i * nb + b] = h[i];
}

__global__ __launch_bounds__(256)
void scanrow2_kernel(int* __restrict__ hist1, int nb1, int* __restrict__ bs1,
                     int* __restrict__ hist2, int nb2, int* __restrict__ bs2) {
    int b = blockIdx.x;
    if (b < NBINS) scan_inplace(hist1 + (size_t)b * nb1, nb1, bs1 + b);
    else           scan_inplace(hist2 + (size_t)(b - NBINS) * nb2, nb2, bs2 + (b - NBINS));
}

__global__ __launch_bounds__(256)
void scanbs_kernel(int* __restrict__ bs1, int* __restrict__ bs2) {
    if (blockIdx.x == 0) scan_inplace(bs1, NBINS, bs1 + NBINS);
    else                 scan_inplace(bs2, NBINS, bs2 + NBINS);
}

__global__ __launch_bounds__(256)
void scatter2_kernel(const int* __restrict__ src1, const int* __restrict__ dst1, int E1, int nb1,
                     const int* __restrict__ hist1, const int* __restrict__ bs1,
                     unsigned int* __restrict__ binned1,
                     const int* __restrict__ src2, const int* __restrict__ dst2, int E2, int nb2,
                     const int* __restrict__ hist2, const int* __restrict__ bs2,
                     unsigned int* __restrict__ binned2) {
    __shared__ int cur[NBINS];
    int blk = blockIdx.x;
    const int *src, *dst, *hist, *bs; int E, nb, b; unsigned int* binned;
    if (blk < nb1) { src = src1; dst = dst1; E = E1; nb = nb1; b = blk; hist = hist1; bs = bs1; binned = binned1; }
    else { src = src2; dst = dst2; E = E2; nb = nb2; b = blk - nb1; hist = hist2; bs = bs2; binned = binned2; }
    int tid = threadIdx.x;
    for (int i = tid; i < NBINS; i += 256)
        cur[i] = hist[(size_t)i * nb + b] + bs[i];
    __syncthreads();
    int e0 = b * CHUNK;
    int e1 = min(E, e0 + CHUNK);
    for (int e = e0 + tid; e < e1; e += 256) {
        int d = dst[e];
        int bb = d >> 8;
        int p = atomicAdd(&cur[bb], 1);   // LDS atomic only
        binned[p] = ((unsigned int)(d & 255) << 16) | (unsigned int)src[e];
    }
}

// per-node degree counts: PB slices per bin, LDS histogram -> global atomic merge
__global__ __launch_bounds__(256)
void count2_kernel(const unsigned int* __restrict__ binned1, const int* __restrict__ bs1,
                   int* __restrict__ cnt1,
                   const unsigned int* __restrict__ binned2, const int* __restrict__ bs2,
                   int* __restrict__ cnt2, int nblk1) {
    __shared__ int h[256];
    int blk = blockIdx.x;
    const unsigned int* binned; const int* bs; int* cnt;
    if (blk < nblk1) { binned = binned1; bs = bs1; cnt = cnt1; }
    else { blk -= nblk1; binned = binned2; bs = bs2; cnt = cnt2; }
    int bin = blk / PB, slice = blk % PB;
    int s = bs[bin], len = bs[bin + 1] - s;
    int i0 = s + (int)((long long)len * slice / PB);
    int i1 = s + (int)((long long)len * (slice + 1) / PB);
    int tid = threadIdx.x;
    h[tid] = 0;
    __syncthreads();
    for (int i = i0 + tid; i < i1; i += 256)
        atomicAdd(&h[binned[i] >> 16], 1);
    __syncthreads();
    int v = h[tid];
    if (v) atomicAdd(&cnt[bin * 256 + tid], v);
}

// per-bin scan of counts -> rowptr, dinv, cursor
__global__ __launch_bounds__(256)
void binscan2_kernel(const int* __restrict__ cnt1, const int* __restrict__ bs1,
                     int* __restrict__ rowptr1, float* __restrict__ dinv1,
                     int* __restrict__ cur1, int E1,
                     const int* __restrict__ cnt2, const int* __restrict__ bs2,
                     int* __restrict__ rowptr2, float* __restrict__ dinv2,
                     int* __restrict__ cur2, int E2) {
    __shared__ int wsum[4];
    int b = blockIdx.x;
    const int *cnt, *bs; int* rowptr; float* dinv; int* cur; int E;
    if (b < NBINS) { cnt = cnt1; bs = bs1; rowptr = rowptr1; dinv = dinv1; cur = cur1; E = E1; }
    else { b -= NBINS; cnt = cnt2; bs = bs2; rowptr = rowptr2; dinv = dinv2; cur = cur2; E = E2; }
    int tid = threadIdx.x, lane = tid & 63, wid = tid >> 6;
    int v = cnt[b * 256 + tid];
    int x = v;
    #pragma unroll
    for (int off = 1; off < 64; off <<= 1) {
        int t = __shfl_up(x, off);
        if (lane >= off) x += t;
    }
    if (lane == 63) wsum[wid] = x;
    __syncthreads();
    int woff = 0;
    #pragma unroll
    for (int w = 0; w < 4; ++w) if (w < wid) woff += wsum[w];
    int pos = bs[b] + woff + x - v;        // exclusive prefix + bin base
    int node = b * 256 + tid;
    cur[b * 256 + tid] = pos;
    if (node < NNODES) {
        rowptr[node] = pos;
        dinv[node] = rsqrtf((float)v + 1.0f);   // +1 self-loop
    }
    if (b == NBINS - 1 && tid == 0) rowptr[NNODES] = E;
}

// place edges: PB slices per bin, global atomic cursor (L2-local col writes)
__global__ __launch_bounds__(256)
void place2_kernel(const unsigned int* __restrict__ binned1, const int* __restrict__ bs1,
                   int* __restrict__ cur1, int* __restrict__ col1,
                   const unsigned int* __restrict__ binned2, const int* __restrict__ bs2,
                   int* __restrict__ cur2, int* __restrict__ col2, int nblk1) {
    int blk = blockIdx.x;
    const unsigned int* binned; const int* bs; int *cur, *col;
    if (blk < nblk1) { binned = binned1; bs = bs1; cur = cur1; col = col1; }
    else { blk -= nblk1; binned = binned2; bs = bs2; cur = cur2; col = col2; }
    int bin = blk / PB, slice = blk % PB;
    int s = bs[bin], len = bs[bin + 1] - s;
    int i0 = s + (int)((long long)len * slice / PB);
    int i1 = s + (int)((long long)len * (slice + 1) / PB);
    for (int i = i0 + threadIdx.x; i < i1; i += 256) {
        unsigned int pk = binned[i];
        int ld = pk >> 16;
        int p = atomicAdd(&cur[bin * 256 + ld], 1);
        col[p] = (int)(pk & 0xffff);
    }
}

// ---- W permute+cast: Wt2[kt][kg][c][kidx] bf16, c<128 -> W1 col, else W2 col ----

__global__ __launch_bounds__(256)
void convW_kernel(const float* __restrict__ W1, const float* __restrict__ W2,
                  unsigned short* __restrict__ Wt2) {
    int k = blockIdx.x;          // 0..511
    int c = threadIdx.x;         // 0..255
    float v = (c < HID) ? W1[(size_t)k * HID + c] : W2[(size_t)k * HID + (c - HID)];
    int kt = k >> 5, kg = (k >> 3) & 3, kidx = k & 7;
    Wt2[(size_t)kt * 8192 + kg * 2048 + c * 8 + kidx] = f2bf(v);
}

// ---- W3 permute+cast: Wt3[kt][kg][c][kidx] bf16 (k in [0,256), c in [0,32)) ----

__global__ __launch_bounds__(256)
void convW3_kernel(const float* __restrict__ W3, unsigned short* __restrict__ Wt3) {
    int idx = blockIdx.x * 256 + threadIdx.x;   // 0..8191
    int k = idx >> 5, c = idx & 31;
    int kt = k >> 5, kg = (k >> 3) & 3, kidx = k & 7;
    Wt3[(kt * 4 + kg) * 256 + c * 8 + kidx] = f2bf(W3[(size_t)k * NCLS + c]);
}

// ---- MFMA GEMM: hs8[r][c] = fp8(64 * dinv_g[r] * (x@Wg)[r][c]) ----

__global__ __launch_bounds__(256)
void gemm12_mfma_kernel(const float* __restrict__ x, const unsigned short* __restrict__ Wt2,
                        const float* __restrict__ dinv1, const float* __restrict__ dinv2,
                        unsigned char* __restrict__ hs8) {
    __shared__ unsigned short Bs[2][8192];   // 2 x 16KB
    int tid = threadIdx.x;
    int wv = tid >> 6, l = tid & 63;
    int lr = l & 15, lg = l >> 4;
    int m0 = blockIdx.x * 64;
    int row = m0 + wv * 16 + lr;
    int rowc = min(row, NNODES - 1);
    const float* xrow = x + (size_t)rowc * DIM;

    f32x4 acc[16];
    #pragma unroll
    for (int n = 0; n < 16; ++n) acc[n] = (f32x4){0.f, 0.f, 0.f, 0.f};

    uint4 bn[4];
    float4 a0, a1, a0n, a1n;
    #pragma unroll
    for (int p = 0; p < 4; ++p)
        bn[p] = *(const uint4*)(Wt2 + p * 2048 + tid * 8);
    a0 = *(const float4*)(xrow + lg * 8);
    a1 = *(const float4*)(xrow + lg * 8 + 4);
    #pragma unroll
    for (int p = 0; p < 4; ++p)
        *(uint4*)(&Bs[0][p * 2048 + tid * 8]) = bn[p];
    __syncthreads();

    int cur = 0;
    for (int kt = 0; kt < 16; ++kt) {
        if (kt < 15) {
            #pragma unroll
            for (int p = 0; p < 4; ++p)
                bn[p] = *(const uint4*)(Wt2 + (size_t)(kt + 1) * 8192 + p * 2048 + tid * 8);
            a0n = *(const float4*)(xrow + (kt + 1) * 32 + lg * 8);
            a1n = *(const float4*)(xrow + (kt + 1) * 32 + lg * 8 + 4);
        }
        union { bf16x8 v; unsigned short u[8]; } af;
        af.u[0] = f2bf(a0.x); af.u[1] = f2bf(a0.y);
        af.u[2] = f2bf(a0.z); af.u[3] = f2bf(a0.w);
        af.u[4] = f2bf(a1.x); af.u[5] = f2bf(a1.y);
        af.u[6] = f2bf(a1.z); af.u[7] = f2bf(a1.w);
        #pragma unroll
        for (int nf = 0; nf < 16; ++nf) {
            bf16x8 bf = *(const bf16x8*)(&Bs[cur][lg * 2048 + (nf * 16 + lr) * 8]);
            acc[nf] = __builtin_amdgcn_mfma_f32_16x16x32_bf16(af.v, bf, acc[nf], 0, 0, 0);
        }
        if (kt < 15) {
            #pragma unroll
            for (int p = 0; p < 4; ++p)
                *(uint4*)(&Bs[cur ^ 1][p * 2048 + tid * 8]) = bn[p];
            __syncthreads();
            cur ^= 1;
            a0 = a0n; a1 = a1n;
        }
    }

    int row0 = m0 + wv * 16 + lg * 4;
    float d1[4], d2[4];
    #pragma unroll
    for (int j = 0; j < 4; ++j) {
        bool ok = (row0 + j) < NNODES;
        d1[j] = ok ? dinv1[row0 + j] * HS_SCALE : 0.f;
        d2[j] = ok ? dinv2[row0 + j] * HS_SCALE : 0.f;
    }
    #pragma unroll
    for (int nf = 0; nf < 16; ++nf) {
        int c = nf * 16 + lr;
        const float* d = (nf < 8) ? d1 : d2;
        #pragma unroll
        for (int j = 0; j < 4; ++j) {
            int r = row0 + j;
            if (r < NNODES)
                hs8[(size_t)r * 256 + c] = f2fp8(acc[nf][j] * d[j]);
        }
    }
}

// ---- aggregate layers 1&2 (edge-balanced waves, fp8 gathers, bf16 out) ----

__global__ __launch_bounds__(256)
void agg12_kernel(const unsigned char* __restrict__ hs8,
                  const int* __restrict__ rowptr1, const int* __restrict__ col1,
                  const int* __restrict__ rowptr2, const int* __restrict__ col2,
                  const float* __restrict__ dinv1, const float* __restrict__ dinv2,
                  const float* __restrict__ b1, const float* __restrict__ b2,
                  int E1, int E2, unsigned short* __restrict__ hcat) {
    int gw = blockIdx.x * 4 + (threadIdx.x >> 6);
    int lane = threadIdx.x & 63;
    int g, w, W; long long E;
    const int *rowptr, *col; const float *dinv, *bias;
    if (gw < AGG_WAVES_G1) {
        g = 0; w = gw; W = AGG_WAVES_G1; E = E1;
        rowptr = rowptr1; col = col1; dinv = dinv1; bias = b1;
    } else {
        g = 1; w = gw - AGG_WAVES_G1; W = AGG_WAVES_G2; E = E2;
        rowptr = rowptr2; col = col2; dinv = dinv2; bias = b2;
    }
    int q0 = (int)(E * w / W);
    int q1 = (int)(E * (w + 1) / W);
    int v0 = lbound(rowptr, q0);
    int v1 = (w == W - 1) ? NNODES : lbound(rowptr, q1);

    int quarter = lane >> 4;       // 0..3 -> edge slot
    int lc = lane & 15;            // col group (8 fp8 each)
    float bias8[8];
    #pragma unroll
    for (int j = 0; j < 8; ++j) bias8[j] = bias[lc * 8 + j];
    const unsigned char* hsg = hs8 + g * 128;

    for (int v = v0; v < v1; ++v) {
        int e0 = rowptr[v], e1 = rowptr[v + 1];
        f32x2 acc[4];
        #pragma unroll
        for (int i = 0; i < 4; ++i) acc[i] = (f32x2){0.f, 0.f};
        int e = e0;
        #pragma unroll 2
        for (; e + 8 <= e1; e += 8) {
            int sA = col[e + quarter];
            int sB = col[e + 4 + quarter];
            uint2 uA = *(const uint2*)(hsg + (size_t)sA * 256 + lc * 8);
            uint2 uB = *(const uint2*)(hsg + (size_t)sB * 256 + lc * 8);
            fp8add2(uA.x, acc[0], acc[1]); fp8add2(uA.y, acc[2], acc[3]);
            fp8add2(uB.x, acc[0], acc[1]); fp8add2(uB.y, acc[2], acc[3]);
        }
        if (e + 4 <= e1) {
            int sA = col[e + quarter];
            uint2 uA = *(const uint2*)(hsg + (size_t)sA * 256 + lc * 8);
            fp8add2(uA.x, acc[0], acc[1]); fp8add2(uA.y, acc[2], acc[3]);
            e += 4;
        }
        if (e < e1 && quarter < e1 - e) {
            int sA = col[e + quarter];
            uint2 uA = *(const uint2*)(hsg + (size_t)sA * 256 + lc * 8);
            fp8add2(uA.x, acc[0], acc[1]); fp8add2(uA.y, acc[2], acc[3]);
        }
        #pragma unroll
        for (int i = 0; i < 4; ++i) {
            #pragma unroll
            for (int off = 16; off <= 32; off <<= 1) {
                acc[i][0] += __shfl_xor(acc[i][0], off);
                acc[i][1] += __shfl_xor(acc[i][1], off);
            }
        }
        uint2 su = *(const uint2*)(hsg + (size_t)v * 256 + lc * 8);
        fp8add2(su.x, acc[0], acc[1]); fp8add2(su.y, acc[2], acc[3]);
        float sc = dinv[v] * HS_ISCALE;
        if (quarter == 0) {
            unsigned int res[4];
            #pragma unroll
            for (int p = 0; p < 4; ++p) {
                float r0 = fmaxf(acc[p][0] * sc + bias8[2 * p + 0], 0.f);
                float r1 = fmaxf(acc[p][1] * sc + bias8[2 * p + 1], 0.f);
                res[p] = (unsigned int)f2bf(r0) | ((unsigned int)f2bf(r1) << 16);
            }
            uint4 st = {res[0], res[1], res[2], res[3]};
            *(uint4*)(hcat + (size_t)v * 256 + g * 128 + lc * 8) = st;
        }
    }
}

// ---- layer-3 MFMA GEMM: gs = bf16(dinv1 * (hcat @ W3)) ----

__global__ __launch_bounds__(256)
void gemm3_mfma_kernel(const unsigned short* __restrict__ hcat,
                       const unsigned short* __restrict__ Wt3,
                       const float* __restrict__ dinv1, unsigned short* __restrict__ gs) {
    __shared__ unsigned short Ws[8192];   // [kt*4+kg][c][8] = 16KB
    int tid = threadIdx.x;
    #pragma unroll
    for (int p = 0; p < 4; ++p)
        *(uint4*)(&Ws[p * 2048 + tid * 8]) = *(const uint4*)(Wt3 + p * 2048 + tid * 8);
    __syncthreads();

    int wv = tid >> 6, l = tid & 63;
    int lr = l & 15, lg = l >> 4;
    int rbase = blockIdx.x * 256 + wv * 64;

    f32x4 acc[4][2];
    #pragma unroll
    for (int m = 0; m < 4; ++m)
        #pragma unroll
        for (int n = 0; n < 2; ++n)
            acc[m][n] = (f32x4){0.f, 0.f, 0.f, 0.f};

    #pragma unroll
    for (int kt = 0; kt < 8; ++kt) {
        #pragma unroll
        for (int m = 0; m < 4; ++m) {
            int rA = min(rbase + m * 16 + lr, NNODES - 1);
            bf16x8 af = *(const bf16x8*)(hcat + (size_t)rA * 256 + kt * 32 + lg * 8);
            #pragma unroll
            for (int n = 0; n < 2; ++n) {
                bf16x8 bf = *(const bf16x8*)(&Ws[(kt * 4 + lg) * 256 + (n * 16 + lr) * 8]);
                acc[m][n] = __builtin_amdgcn_mfma_f32_16x16x32_bf16(af, bf, acc[m][n], 0, 0, 0);
            }
        }
    }

    #pragma unroll
    for (int m = 0; m < 4; ++m) {
        int row0 = rbase + m * 16 + lg * 4;
        float d[4];
        #pragma unroll
        for (int j = 0; j < 4; ++j)
            d[j] = (row0 + j < NNODES) ? dinv1[row0 + j] : 0.f;
        #pragma unroll
        for (int n = 0; n < 2; ++n) {
            int c = n * 16 + lr;
            #pragma unroll
            for (int j = 0; j < 4; ++j) {
                int r = row0 + j;
                if (r < NNODES)
                    gs[(size_t)r * 32 + c] = f2bf(acc[m][n][j] * d[j]);
            }
        }
    }
}

// ---- layer-3 aggregation + bias + log_softmax (edge-balanced, gs bf16) ----

__global__ __launch_bounds__(256)
void agg3_kernel(const unsigned short* __restrict__ gs, const int* __restrict__ rowptr1,
                 const int* __restrict__ col1, const float* __restrict__ dinv1,
                 const float* __restrict__ b3, float* __restrict__ out, int E1) {
    int gw = blockIdx.x * 4 + (threadIdx.x >> 6);
    int lane = threadIdx.x & 63;
    long long E = E1;
    int q0 = (int)(E * gw / A3_WAVES);
    int q1 = (int)(E * (gw + 1) / A3_WAVES);
    int v0 = lbound(rowptr1, q0);
    int v1 = (gw == A3_WAVES - 1) ? NNODES : lbound(rowptr1, q1);

    int oct = lane >> 3;         // 0..7 -> edge slot
    int lc = lane & 7;           // col group (4 vals each)
    float4 b3v = *(const float4*)(b3 + lc * 4);

    for (int v = v0; v < v1; ++v) {
        int e0 = rowptr1[v], e1 = rowptr1[v + 1];
        float a0 = 0.f, a1 = 0.f, a2 = 0.f, a3 = 0.f;
        int e = e0;
        #pragma unroll 2
        for (; e + 8 <= e1; e += 8) {
            int srco = col1[e + oct];
            uint2 u = *(const uint2*)(gs + (size_t)srco * 32 + lc * 4);
            a0 += bf2f((unsigned short)(u.x & 0xffff));
            a1 += bf2f((unsigned short)(u.x >> 16));
            a2 += bf2f((unsigned short)(u.y & 0xffff));
            a3 += bf2f((unsigned short)(u.y >> 16));
        }
        if (e < e1) {
            int r = e1 - e;
            if (oct < r) {
                int srco = col1[e + oct];
                uint2 u = *(const uint2*)(gs + (size_t)srco * 32 + lc * 4);
                a0 += bf2f((unsigned short)(u.x & 0xffff));
                a1 += bf2f((unsigned short)(u.x >> 16));
                a2 += bf2f((unsigned short)(u.y & 0xffff));
                a3 += bf2f((unsigned short)(u.y >> 16));
            }
        }
        #pragma unroll
        for (int off = 32; off >= 8; off >>= 1) {
            a0 += __shfl_xor(a0, off); a1 += __shfl_xor(a1, off);
            a2 += __shfl_xor(a2, off); a3 += __shfl_xor(a3, off);
        }
        uint2 su = *(const uint2*)(gs + (size_t)v * 32 + lc * 4);
        a0 += bf2f((unsigned short)(su.x & 0xffff));
        a1 += bf2f((unsigned short)(su.x >> 16));
        a2 += bf2f((unsigned short)(su.y & 0xffff));
        a3 += bf2f((unsigned short)(su.y >> 16));
        float d = dinv1[v];
        float l0 = a0 * d + b3v.x, l1 = a1 * d + b3v.y;
        float l2 = a2 * d + b3v.z, l3 = a3 * d + b3v.w;
        float m = fmaxf(fmaxf(l0, l1), fmaxf(l2, l3));
        #pragma unroll
        for (int off = 1; off <= 4; off <<= 1) m = fmaxf(m, __shfl_xor(m, off));
        float s = expf(l0 - m) + expf(l1 - m) + expf(l2 - m) + expf(l3 - m);
        #pragma unroll
        for (int off = 1; off <= 4; off <<= 1) s += __shfl_xor(s, off);
        float lg = logf(s);
        if (oct == 0) {
            float4 o = make_float4(l0 - m - lg, l1 - m - lg, l2 - m - lg, l3 - m - lg);
            *(float4*)(out + (size_t)v * 32 + lc * 4) = o;
        }
    }
}

extern "C" void kernel_launch(void* const* d_in, const int* in_sizes, int n_in,
                              void* d_out, int out_size, void* d_ws, size_t ws_size,
                              hipStream_t stream) {
    const float* x  = (const float*)d_in[0];
    const int* ei1  = (const int*)d_in[1];
    const int* ei2  = (const int*)d_in[2];
    const float* W1 = (const float*)d_in[3];
    const float* b1 = (const float*)d_in[4];
    const float* W2 = (const float*)d_in[5];
    const float* b2 = (const float*)d_in[6];
    const float* W3 = (const float*)d_in[7];
    const float* b3 = (const float*)d_in[8];
    float* out = (float*)d_out;

    int E1 = in_sizes[1] / 2;
    int E2 = in_sizes[2] / 2;
    const int* src1 = ei1;       const int* dst1 = ei1 + E1;
    const int* src2 = ei2;       const int* dst2 = ei2 + E2;
    int nb1 = (E1 + CHUNK - 1) / CHUNK;
    int nb2 = (E2 + CHUNK - 1) / CHUNK;

    char* w = (char*)d_ws;
    auto alloc = [&](size_t bytes) -> char* {
        char* p = w; w += (bytes + 255) & ~(size_t)255; return p;
    };
    int* hist1   = (int*)alloc((size_t)NBINS * nb1 * 4);
    int* hist2   = (int*)alloc((size_t)NBINS * nb2 * 4);
    int* bs1     = (int*)alloc((size_t)(NBINS + 1) * 4);
    int* bs2     = (int*)alloc((size_t)(NBINS + 1) * 4);
    int* rowptr1 = (int*)alloc((size_t)(NNODES + 1) * 4);
    int* rowptr2 = (int*)alloc((size_t)(NNODES + 1) * 4);
    float* dinv1 = (float*)alloc((size_t)NNODES * 4);
    float* dinv2 = (float*)alloc((size_t)NNODES * 4);
    int* cnt1    = (int*)alloc((size_t)NBINS * 256 * 4);
    int* cnt2    = (int*)alloc((size_t)NBINS * 256 * 4);
    int* cur1    = (int*)alloc((size_t)NBINS * 256 * 4);
    int* cur2    = (int*)alloc((size_t)NBINS * 256 * 4);
    int* col1    = (int*)alloc((size_t)E1 * 4);
    int* col2    = (int*)alloc((size_t)E2 * 4);
    unsigned short* Wt2 = (unsigned short*)alloc((size_t)256 * DIM * 2);
    unsigned short* Wt3 = (unsigned short*)alloc((size_t)256 * NCLS * 2);
    unsigned char* hs8 = (unsigned char*)alloc((size_t)NNODES * 256);
    unsigned short* gs = (unsigned short*)alloc((size_t)NNODES * 32 * 2);
    unsigned short* hcat = (unsigned short*)alloc((size_t)NNODES * 256 * 2);
    // binned arrays alias hcat (dead before agg12 writes hcat); 19.4MB <= 25.6MB
    unsigned int* binned1 = (unsigned int*)hcat;
    unsigned int* binned2 = binned1 + E1;

    hipMemsetAsync(cnt1, 0, (size_t)NBINS * 256 * 4, stream);
    hipMemsetAsync(cnt2, 0, (size_t)NBINS * 256 * 4, stream);

    hist2_kernel<<<nb1 + nb2, 256, 0, stream>>>(dst1, E1, nb1, hist1, dst2, E2, nb2, hist2);
    scanrow2_kernel<<<NBINS * 2, 256, 0, stream>>>(hist1, nb1, bs1, hist2, nb2, bs2);
    scanbs_kernel<<<2, 256, 0, stream>>>(bs1, bs2);
    scatter2_kernel<<<nb1 + nb2, 256, 0, stream>>>(src1, dst1, E1, nb1, hist1, bs1, binned1,
                                                   src2, dst2, E2, nb2, hist2, bs2, binned2);
    count2_kernel<<<NBINS * PB * 2, 256, 0, stream>>>(binned1, bs1, cnt1,
                                                      binned2, bs2, cnt2, NBINS * PB);
    binscan2_kernel<<<NBINS * 2, 256, 0, stream>>>(cnt1, bs1, rowptr1, dinv1, cur1, E1,
                                                   cnt2, bs2, rowptr2, dinv2, cur2, E2);
    place2_kernel<<<NBINS * PB * 2, 256, 0, stream>>>(binned1, bs1, cur1, col1,
                                                      binned2, bs2, cur2, col2, NBINS * PB);

    convW_kernel<<<DIM, 256, 0, stream>>>(W1, W2, Wt2);
    convW3_kernel<<<32, 256, 0, stream>>>(W3, Wt3);
    gemm12_mfma_kernel<<<(NNODES + 63) / 64, 256, 0, stream>>>(x, Wt2, dinv1, dinv2, hs8);
    agg12_kernel<<<(AGG_WAVES_G1 + AGG_WAVES_G2) / 4, 256, 0, stream>>>(
        hs8, rowptr1, col1, rowptr2, col2, dinv1, dinv2, b1, b2, E1, E2, hcat);
    gemm3_mfma_kernel<<<(NNODES + 255) / 256, 256, 0, stream>>>(hcat, Wt3, dinv1, gs);
    agg3_kernel<<<A3_WAVES / 4, 256, 0, stream>>>(gs, rowptr1, col1, dinv1, b3, out, E1);
}

// Round 9
// 369.589 us; speedup vs baseline: 1.0602x; 1.0602x over previous
//
#include <hip/hip_runtime.h>

#define NNODES 50000
#define DIM 512
#define HID 128
#define NCLS 32
#define NBINS 196          // ceil(50000 / 256), bin = dst >> 8
#define CHUNK 8192         // edges per block in hist/scatter passes
#define AGG_WAVES_G1 2048
#define AGG_WAVES_G2 4096
#define A3_WAVES 4096
#define HS_SCALE 64.0f
#define HS_ISCALE 0.015625f

typedef __attribute__((ext_vector_type(8))) short bf16x8;
typedef __attribute__((ext_vector_type(4))) float f32x4;
typedef __attribute__((ext_vector_type(2))) float f32x2;

__device__ __forceinline__ unsigned short f2bf(float f) {
    union { float f; unsigned int u; } a; a.f = f;
    unsigned int u = a.u;
    u += 0x7fff + ((u >> 16) & 1);   // round-to-nearest-even
    return (unsigned short)(u >> 16);
}
__device__ __forceinline__ float bf2f(unsigned short h) {
    union { unsigned int u; float f; } a; a.u = ((unsigned int)h) << 16;
    return a.f;
}
// f32 -> fp8 e4m3 (OCP on gfx950), RNE
__device__ __forceinline__ unsigned char f2fp8(float f) {
    int p = __builtin_amdgcn_cvt_pk_fp8_f32(f, 0.f, 0, false);
    return (unsigned char)(p & 0xff);
}
// 4 packed fp8 -> two f32x2 accumulators (v_pk_add_f32)
__device__ __forceinline__ void fp8add2(unsigned int u, f32x2& a01, f32x2& a23) {
    a01 += __builtin_amdgcn_cvt_pk_f32_fp8((int)u, false);
    a23 += __builtin_amdgcn_cvt_pk_f32_fp8((int)u, true);
}
// min v in [0,NNODES] with rp[v] >= q
__device__ __forceinline__ int lbound(const int* __restrict__ rp, int q) {
    int lo = 0, hi = NNODES;
    while (lo < hi) { int mid = (lo + hi) >> 1; if (rp[mid] >= q) hi = mid; else lo = mid + 1; }
    return lo;
}
// in-place exclusive scan of row[0..n), block of 256; row sum -> *total
__device__ __forceinline__ void scan_inplace(int* __restrict__ row, int n, int* __restrict__ total) {
    __shared__ int wsum[4];
    int tid = threadIdx.x, lane = tid & 63, wid = tid >> 6;
    int base = 0;
    for (int start = 0; start < n; start += 256) {
        int i = start + tid;
        int v = (i < n) ? row[i] : 0;
        int x = v;
        #pragma unroll
        for (int off = 1; off < 64; off <<= 1) {
            int t = __shfl_up(x, off);
            if (lane >= off) x += t;
        }
        if (lane == 63) wsum[wid] = x;
        __syncthreads();
        int woff = 0, tot = 0;
        #pragma unroll
        for (int w = 0; w < 4; ++w) { int s = wsum[w]; if (w < wid) woff += s; tot += s; }
        __syncthreads();
        if (i < n) row[i] = base + woff + x - v;
        base += tot;
    }
    if (tid == 0) *total = base;
}

// ============ deterministic CSR build (r7 algorithms, merged launches) ============

__global__ __launch_bounds__(256)
void hist2_kernel(const int* __restrict__ dst1, int E1, int nb1, int* __restrict__ hist1,
                  const int* __restrict__ dst2, int E2, int nb2, int* __restrict__ hist2) {
    __shared__ int h[NBINS];
    int blk = blockIdx.x;
    const int* dst; int E, nb, b; int* hist;
    if (blk < nb1) { dst = dst1; E = E1; nb = nb1; b = blk; hist = hist1; }
    else { dst = dst2; E = E2; nb = nb2; b = blk - nb1; hist = hist2; }
    int tid = threadIdx.x;
    for (int i = tid; i < NBINS; i += 256) h[i] = 0;
    __syncthreads();
    int e0 = b * CHUNK;
    int e1 = min(E, e0 + CHUNK);
    for (int e = e0 + tid; e < e1; e += 256)
        atomicAdd(&h[dst[e] >> 8], 1);
    __syncthreads();
    for (int i = tid; i < NBINS; i += 256)
        hist[(size_t)i * nb + b] = h[i];
}

__global__ __launch_bounds__(256)
void scanrow2_kernel(int* __restrict__ hist1, int nb1, int* __restrict__ bs1,
                     int* __restrict__ hist2, int nb2, int* __restrict__ bs2) {
    int b = blockIdx.x;
    if (b < NBINS) scan_inplace(hist1 + (size_t)b * nb1, nb1, bs1 + b);
    else           scan_inplace(hist2 + (size_t)(b - NBINS) * nb2, nb2, bs2 + (b - NBINS));
}

__global__ __launch_bounds__(256)
void scanbs_kernel(int* __restrict__ bs1, int* __restrict__ bs2) {
    if (blockIdx.x == 0) scan_inplace(bs1, NBINS, bs1 + NBINS);
    else                 scan_inplace(bs2, NBINS, bs2 + NBINS);
}

__global__ __launch_bounds__(256)
void scatter2_kernel(const int* __restrict__ src1, const int* __restrict__ dst1, int E1, int nb1,
                     const int* __restrict__ hist1, const int* __restrict__ bs1,
                     unsigned int* __restrict__ binned1,
                     const int* __restrict__ src2, const int* __restrict__ dst2, int E2, int nb2,
                     const int* __restrict__ hist2, const int* __restrict__ bs2,
                     unsigned int* __restrict__ binned2) {
    __shared__ int cur[NBINS];
    int blk = blockIdx.x;
    const int *src, *dst, *hist, *bs; int E, nb, b; unsigned int* binned;
    if (blk < nb1) { src = src1; dst = dst1; E = E1; nb = nb1; b = blk; hist = hist1; bs = bs1; binned = binned1; }
    else { src = src2; dst = dst2; E = E2; nb = nb2; b = blk - nb1; hist = hist2; bs = bs2; binned = binned2; }
    int tid = threadIdx.x;
    for (int i = tid; i < NBINS; i += 256)
        cur[i] = hist[(size_t)i * nb + b] + bs[i];
    __syncthreads();
    int e0 = b * CHUNK;
    int e1 = min(E, e0 + CHUNK);
    for (int e = e0 + tid; e < e1; e += 256) {
        int d = dst[e];
        int bb = d >> 8;
        int p = atomicAdd(&cur[bb], 1);   // LDS atomic only
        binned[p] = ((unsigned int)(d & 255) << 16) | (unsigned int)src[e];
    }
}

// one block per (graph, bin): per-node count -> scan -> rowptr/dinv -> col fill
__global__ __launch_bounds__(256)
void binfill2_kernel(const unsigned int* __restrict__ binned1, const int* __restrict__ bs1,
                     int* __restrict__ rowptr1, float* __restrict__ dinv1,
                     int* __restrict__ col1, int E1,
                     const unsigned int* __restrict__ binned2, const int* __restrict__ bs2,
                     int* __restrict__ rowptr2, float* __restrict__ dinv2,
                     int* __restrict__ col2, int E2) {
    __shared__ int cnt[256], cur[256];
    __shared__ int wsum[4];
    int b = blockIdx.x;
    const unsigned int* binned; const int* bs; int* rowptr; float* dinv; int* col; int totalE;
    if (b < NBINS) { binned = binned1; bs = bs1; rowptr = rowptr1; dinv = dinv1; col = col1; totalE = E1; }
    else { b -= NBINS; binned = binned2; bs = bs2; rowptr = rowptr2; dinv = dinv2; col = col2; totalE = E2; }
    int tid = threadIdx.x, lane = tid & 63, wid = tid >> 6;
    int s = bs[b], e = bs[b + 1];
    cnt[tid] = 0;
    __syncthreads();
    for (int i = s + tid; i < e; i += 256)
        atomicAdd(&cnt[binned[i] >> 16], 1);
    __syncthreads();
    int v = cnt[tid];
    int x = v;
    #pragma unroll
    for (int off = 1; off < 64; off <<= 1) {
        int t = __shfl_up(x, off);
        if (lane >= off) x += t;
    }
    if (lane == 63) wsum[wid] = x;
    __syncthreads();
    int woff = 0;
    #pragma unroll
    for (int w = 0; w < 4; ++w) if (w < wid) woff += wsum[w];
    int ex = woff + x - v;               // exclusive prefix within bin
    cur[tid] = ex;
    __syncthreads();
    int node = b * 256 + tid;
    if (node < NNODES) {
        rowptr[node] = s + ex;
        dinv[node] = rsqrtf((float)v + 1.0f);   // +1 self-loop
    }
    if (b == 0 && tid == 0) rowptr[NNODES] = totalE;
    for (int i = s + tid; i < e; i += 256) {
        unsigned int pk = binned[i];
        int ld = pk >> 16;
        int p = atomicAdd(&cur[ld], 1);  // LDS atomic only
        col[s + p] = (int)(pk & 0xffff);
    }
}

// ---- W permute+cast: Wt2[kt][kg][c][kidx] bf16, c<128 -> W1 col, else W2 col ----

__global__ __launch_bounds__(256)
void convW_kernel(const float* __restrict__ W1, const float* __restrict__ W2,
                  unsigned short* __restrict__ Wt2) {
    int k = blockIdx.x;          // 0..511
    int c = threadIdx.x;         // 0..255
    float v = (c < HID) ? W1[(size_t)k * HID + c] : W2[(size_t)k * HID + (c - HID)];
    int kt = k >> 5, kg = (k >> 3) & 3, kidx = k & 7;
    Wt2[(size_t)kt * 8192 + kg * 2048 + c * 8 + kidx] = f2bf(v);
}

// ---- W3 permute+cast: Wt3[kt][kg][c][kidx] bf16 (k in [0,256), c in [0,32)) ----

__global__ __launch_bounds__(256)
void convW3_kernel(const float* __restrict__ W3, unsigned short* __restrict__ Wt3) {
    int idx = blockIdx.x * 256 + threadIdx.x;   // 0..8191
    int k = idx >> 5, c = idx & 31;
    int kt = k >> 5, kg = (k >> 3) & 3, kidx = k & 7;
    Wt3[(kt * 4 + kg) * 256 + c * 8 + kidx] = f2bf(W3[(size_t)k * NCLS + c]);
}

// ---- MFMA GEMM: hs8[r][c] = fp8(64 * dinv_g[r] * (x@Wg)[r][c]) ----

__global__ __launch_bounds__(256)
void gemm12_mfma_kernel(const float* __restrict__ x, const unsigned short* __restrict__ Wt2,
                        const float* __restrict__ dinv1, const float* __restrict__ dinv2,
                        unsigned char* __restrict__ hs8) {
    __shared__ unsigned short Bs[2][8192];   // 2 x 16KB
    int tid = threadIdx.x;
    int wv = tid >> 6, l = tid & 63;
    int lr = l & 15, lg = l >> 4;
    int m0 = blockIdx.x * 64;
    int row = m0 + wv * 16 + lr;
    int rowc = min(row, NNODES - 1);
    const float* xrow = x + (size_t)rowc * DIM;

    f32x4 acc[16];
    #pragma unroll
    for (int n = 0; n < 16; ++n) acc[n] = (f32x4){0.f, 0.f, 0.f, 0.f};

    uint4 bn[4];
    float4 a0, a1, a0n, a1n;
    #pragma unroll
    for (int p = 0; p < 4; ++p)
        bn[p] = *(const uint4*)(Wt2 + p * 2048 + tid * 8);
    a0 = *(const float4*)(xrow + lg * 8);
    a1 = *(const float4*)(xrow + lg * 8 + 4);
    #pragma unroll
    for (int p = 0; p < 4; ++p)
        *(uint4*)(&Bs[0][p * 2048 + tid * 8]) = bn[p];
    __syncthreads();

    int cur = 0;
    for (int kt = 0; kt < 16; ++kt) {
        if (kt < 15) {
            #pragma unroll
            for (int p = 0; p < 4; ++p)
                bn[p] = *(const uint4*)(Wt2 + (size_t)(kt + 1) * 8192 + p * 2048 + tid * 8);
            a0n = *(const float4*)(xrow + (kt + 1) * 32 + lg * 8);
            a1n = *(const float4*)(xrow + (kt + 1) * 32 + lg * 8 + 4);
        }
        union { bf16x8 v; unsigned short u[8]; } af;
        af.u[0] = f2bf(a0.x); af.u[1] = f2bf(a0.y);
        af.u[2] = f2bf(a0.z); af.u[3] = f2bf(a0.w);
        af.u[4] = f2bf(a1.x); af.u[5] = f2bf(a1.y);
        af.u[6] = f2bf(a1.z); af.u[7] = f2bf(a1.w);
        #pragma unroll
        for (int nf = 0; nf < 16; ++nf) {
            bf16x8 bf = *(const bf16x8*)(&Bs[cur][lg * 2048 + (nf * 16 + lr) * 8]);
            acc[nf] = __builtin_amdgcn_mfma_f32_16x16x32_bf16(af.v, bf, acc[nf], 0, 0, 0);
        }
        if (kt < 15) {
            #pragma unroll
            for (int p = 0; p < 4; ++p)
                *(uint4*)(&Bs[cur ^ 1][p * 2048 + tid * 8]) = bn[p];
            __syncthreads();
            cur ^= 1;
            a0 = a0n; a1 = a1n;
        }
    }

    int row0 = m0 + wv * 16 + lg * 4;
    float d1[4], d2[4];
    #pragma unroll
    for (int j = 0; j < 4; ++j) {
        bool ok = (row0 + j) < NNODES;
        d1[j] = ok ? dinv1[row0 + j] * HS_SCALE : 0.f;
        d2[j] = ok ? dinv2[row0 + j] * HS_SCALE : 0.f;
    }
    #pragma unroll
    for (int nf = 0; nf < 16; ++nf) {
        int c = nf * 16 + lr;
        const float* d = (nf < 8) ? d1 : d2;
        #pragma unroll
        for (int j = 0; j < 4; ++j) {
            int r = row0 + j;
            if (r < NNODES)
                hs8[(size_t)r * 256 + c] = f2fp8(acc[nf][j] * d[j]);
        }
    }
}

// ---- aggregate layers 1&2 (edge-balanced waves, lane-octet uint4 gathers) ----
// 8 edges in flight per iteration: oct handles edge e+oct, one dwordx4 = 16 fp8/lane.

__global__ __launch_bounds__(256)
void agg12_kernel(const unsigned char* __restrict__ hs8,
                  const int* __restrict__ rowptr1, const int* __restrict__ col1,
                  const int* __restrict__ rowptr2, const int* __restrict__ col2,
                  const float* __restrict__ dinv1, const float* __restrict__ dinv2,
                  const float* __restrict__ b1, const float* __restrict__ b2,
                  int E1, int E2, unsigned short* __restrict__ hcat) {
    int gw = blockIdx.x * 4 + (threadIdx.x >> 6);
    int lane = threadIdx.x & 63;
    int g, w, W; long long E;
    const int *rowptr, *col; const float *dinv, *bias;
    if (gw < AGG_WAVES_G1) {
        g = 0; w = gw; W = AGG_WAVES_G1; E = E1;
        rowptr = rowptr1; col = col1; dinv = dinv1; bias = b1;
    } else {
        g = 1; w = gw - AGG_WAVES_G1; W = AGG_WAVES_G2; E = E2;
        rowptr = rowptr2; col = col2; dinv = dinv2; bias = b2;
    }
    int q0 = (int)(E * w / W);
    int q1 = (int)(E * (w + 1) / W);
    int v0 = lbound(rowptr, q0);
    int v1 = (w == W - 1) ? NNODES : lbound(rowptr, q1);

    int oct = lane >> 3;           // 0..7 -> edge slot
    int lc = lane & 7;             // col group: 16 fp8 at lc*16
    float bias16[16];
    #pragma unroll
    for (int j = 0; j < 16; ++j) bias16[j] = bias[lc * 16 + j];
    const unsigned char* hsg = hs8 + g * 128;

    for (int v = v0; v < v1; ++v) {
        int e0 = rowptr[v], e1 = rowptr[v + 1];
        f32x2 acc[8];
        #pragma unroll
        for (int i = 0; i < 8; ++i) acc[i] = (f32x2){0.f, 0.f};
        int e = e0;
        for (; e + 16 <= e1; e += 16) {
            int sA = col[e + oct];
            int sB = col[e + 8 + oct];
            uint4 uA = *(const uint4*)(hsg + (size_t)sA * 256 + lc * 16);
            uint4 uB = *(const uint4*)(hsg + (size_t)sB * 256 + lc * 16);
            fp8add2(uA.x, acc[0], acc[1]); fp8add2(uA.y, acc[2], acc[3]);
            fp8add2(uA.z, acc[4], acc[5]); fp8add2(uA.w, acc[6], acc[7]);
            fp8add2(uB.x, acc[0], acc[1]); fp8add2(uB.y, acc[2], acc[3]);
            fp8add2(uB.z, acc[4], acc[5]); fp8add2(uB.w, acc[6], acc[7]);
        }
        if (e + 8 <= e1) {
            int sA = col[e + oct];
            uint4 uA = *(const uint4*)(hsg + (size_t)sA * 256 + lc * 16);
            fp8add2(uA.x, acc[0], acc[1]); fp8add2(uA.y, acc[2], acc[3]);
            fp8add2(uA.z, acc[4], acc[5]); fp8add2(uA.w, acc[6], acc[7]);
            e += 8;
        }
        if (e < e1 && oct < e1 - e) {
            int sA = col[e + oct];
            uint4 uA = *(const uint4*)(hsg + (size_t)sA * 256 + lc * 16);
            fp8add2(uA.x, acc[0], acc[1]); fp8add2(uA.y, acc[2], acc[3]);
            fp8add2(uA.z, acc[4], acc[5]); fp8add2(uA.w, acc[6], acc[7]);
        }
        #pragma unroll
        for (int i = 0; i < 8; ++i) {
            #pragma unroll
            for (int off = 8; off <= 32; off <<= 1) {
                acc[i][0] += __shfl_xor(acc[i][0], off);
                acc[i][1] += __shfl_xor(acc[i][1], off);
            }
        }
        // self term (post-reduce, consistent across lanes sharing lc)
        uint4 su = *(const uint4*)(hsg + (size_t)v * 256 + lc * 16);
        fp8add2(su.x, acc[0], acc[1]); fp8add2(su.y, acc[2], acc[3]);
        fp8add2(su.z, acc[4], acc[5]); fp8add2(su.w, acc[6], acc[7]);
        float sc = dinv[v] * HS_ISCALE;
        if (oct == 0) {
            unsigned int res[8];
            #pragma unroll
            for (int p = 0; p < 8; ++p) {
                float r0 = fmaxf(acc[p][0] * sc + bias16[2 * p + 0], 0.f);
                float r1 = fmaxf(acc[p][1] * sc + bias16[2 * p + 1], 0.f);
                res[p] = (unsigned int)f2bf(r0) | ((unsigned int)f2bf(r1) << 16);
            }
            unsigned short* dst = hcat + (size_t)v * 256 + g * 128 + lc * 16;
            uint4 st0 = {res[0], res[1], res[2], res[3]};
            uint4 st1 = {res[4], res[5], res[6], res[7]};
            *(uint4*)(dst) = st0;
            *(uint4*)(dst + 8) = st1;
        }
    }
}

// ---- layer-3 MFMA GEMM: gs = bf16(dinv1 * (hcat @ W3)) ----

__global__ __launch_bounds__(256)
void gemm3_mfma_kernel(const unsigned short* __restrict__ hcat,
                       const unsigned short* __restrict__ Wt3,
                       const float* __restrict__ dinv1, unsigned short* __restrict__ gs) {
    __shared__ unsigned short Ws[8192];   // [kt*4+kg][c][8] = 16KB
    int tid = threadIdx.x;
    #pragma unroll
    for (int p = 0; p < 4; ++p)
        *(uint4*)(&Ws[p * 2048 + tid * 8]) = *(const uint4*)(Wt3 + p * 2048 + tid * 8);
    __syncthreads();

    int wv = tid >> 6, l = tid & 63;
    int lr = l & 15, lg = l >> 4;
    int rbase = blockIdx.x * 256 + wv * 64;

    f32x4 acc[4][2];
    #pragma unroll
    for (int m = 0; m < 4; ++m)
        #pragma unroll
        for (int n = 0; n < 2; ++n)
            acc[m][n] = (f32x4){0.f, 0.f, 0.f, 0.f};

    #pragma unroll
    for (int kt = 0; kt < 8; ++kt) {
        #pragma unroll
        for (int m = 0; m < 4; ++m) {
            int rA = min(rbase + m * 16 + lr, NNODES - 1);
            bf16x8 af = *(const bf16x8*)(hcat + (size_t)rA * 256 + kt * 32 + lg * 8);
            #pragma unroll
            for (int n = 0; n < 2; ++n) {
                bf16x8 bf = *(const bf16x8*)(&Ws[(kt * 4 + lg) * 256 + (n * 16 + lr) * 8]);
                acc[m][n] = __builtin_amdgcn_mfma_f32_16x16x32_bf16(af, bf, acc[m][n], 0, 0, 0);
            }
        }
    }

    #pragma unroll
    for (int m = 0; m < 4; ++m) {
        int row0 = rbase + m * 16 + lg * 4;
        float d[4];
        #pragma unroll
        for (int j = 0; j < 4; ++j)
            d[j] = (row0 + j < NNODES) ? dinv1[row0 + j] : 0.f;
        #pragma unroll
        for (int n = 0; n < 2; ++n) {
            int c = n * 16 + lr;
            #pragma unroll
            for (int j = 0; j < 4; ++j) {
                int r = row0 + j;
                if (r < NNODES)
                    gs[(size_t)r * 32 + c] = f2bf(acc[m][n][j] * d[j]);
            }
        }
    }
}

// ---- layer-3 aggregation + bias + log_softmax (edge-balanced, gs bf16) ----

__global__ __launch_bounds__(256)
void agg3_kernel(const unsigned short* __restrict__ gs, const int* __restrict__ rowptr1,
                 const int* __restrict__ col1, const float* __restrict__ dinv1,
                 const float* __restrict__ b3, float* __restrict__ out, int E1) {
    int gw = blockIdx.x * 4 + (threadIdx.x >> 6);
    int lane = threadIdx.x & 63;
    long long E = E1;
    int q0 = (int)(E * gw / A3_WAVES);
    int q1 = (int)(E * (gw + 1) / A3_WAVES);
    int v0 = lbound(rowptr1, q0);
    int v1 = (gw == A3_WAVES - 1) ? NNODES : lbound(rowptr1, q1);

    int oct = lane >> 3;         // 0..7 -> edge slot
    int lc = lane & 7;           // col group (4 vals each)
    float4 b3v = *(const float4*)(b3 + lc * 4);

    for (int v = v0; v < v1; ++v) {
        int e0 = rowptr1[v], e1 = rowptr1[v + 1];
        float a0 = 0.f, a1 = 0.f, a2 = 0.f, a3 = 0.f;
        int e = e0;
        #pragma unroll 2
        for (; e + 8 <= e1; e += 8) {
            int srco = col1[e + oct];
            uint2 u = *(const uint2*)(gs + (size_t)srco * 32 + lc * 4);
            a0 += bf2f((unsigned short)(u.x & 0xffff));
            a1 += bf2f((unsigned short)(u.x >> 16));
            a2 += bf2f((unsigned short)(u.y & 0xffff));
            a3 += bf2f((unsigned short)(u.y >> 16));
        }
        if (e < e1) {
            int r = e1 - e;
            if (oct < r) {
                int srco = col1[e + oct];
                uint2 u = *(const uint2*)(gs + (size_t)srco * 32 + lc * 4);
                a0 += bf2f((unsigned short)(u.x & 0xffff));
                a1 += bf2f((unsigned short)(u.x >> 16));
                a2 += bf2f((unsigned short)(u.y & 0xffff));
                a3 += bf2f((unsigned short)(u.y >> 16));
            }
        }
        #pragma unroll
        for (int off = 32; off >= 8; off >>= 1) {
            a0 += __shfl_xor(a0, off); a1 += __shfl_xor(a1, off);
            a2 += __shfl_xor(a2, off); a3 += __shfl_xor(a3, off);
        }
        uint2 su = *(const uint2*)(gs + (size_t)v * 32 + lc * 4);
        a0 += bf2f((unsigned short)(su.x & 0xffff));
        a1 += bf2f((unsigned short)(su.x >> 16));
        a2 += bf2f((unsigned short)(su.y & 0xffff));
        a3 += bf2f((unsigned short)(su.y >> 16));
        float d = dinv1[v];
        float l0 = a0 * d + b3v.x, l1 = a1 * d + b3v.y;
        float l2 = a2 * d + b3v.z, l3 = a3 * d + b3v.w;
        float m = fmaxf(fmaxf(l0, l1), fmaxf(l2, l3));
        #pragma unroll
        for (int off = 1; off <= 4; off <<= 1) m = fmaxf(m, __shfl_xor(m, off));
        float s = expf(l0 - m) + expf(l1 - m) + expf(l2 - m) + expf(l3 - m);
        #pragma unroll
        for (int off = 1; off <= 4; off <<= 1) s += __shfl_xor(s, off);
        float lg = logf(s);
        if (oct == 0) {
            float4 o = make_float4(l0 - m - lg, l1 - m - lg, l2 - m - lg, l3 - m - lg);
            *(float4*)(out + (size_t)v * 32 + lc * 4) = o;
        }
    }
}

extern "C" void kernel_launch(void* const* d_in, const int* in_sizes, int n_in,
                              void* d_out, int out_size, void* d_ws, size_t ws_size,
                              hipStream_t stream) {
    const float* x  = (const float*)d_in[0];
    const int* ei1  = (const int*)d_in[1];
    const int* ei2  = (const int*)d_in[2];
    const float* W1 = (const float*)d_in[3];
    const float* b1 = (const float*)d_in[4];
    const float* W2 = (const float*)d_in[5];
    const float* b2 = (const float*)d_in[6];
    const float* W3 = (const float*)d_in[7];
    const float* b3 = (const float*)d_in[8];
    float* out = (float*)d_out;

    int E1 = in_sizes[1] / 2;
    int E2 = in_sizes[2] / 2;
    const int* src1 = ei1;       const int* dst1 = ei1 + E1;
    const int* src2 = ei2;       const int* dst2 = ei2 + E2;
    int nb1 = (E1 + CHUNK - 1) / CHUNK;
    int nb2 = (E2 + CHUNK - 1) / CHUNK;

    char* w = (char*)d_ws;
    auto alloc = [&](size_t bytes) -> char* {
        char* p = w; w += (bytes + 255) & ~(size_t)255; return p;
    };
    int* hist1   = (int*)alloc((size_t)NBINS * nb1 * 4);
    int* hist2   = (int*)alloc((size_t)NBINS * nb2 * 4);
    int* bs1     = (int*)alloc((size_t)(NBINS + 1) * 4);
    int* bs2     = (int*)alloc((size_t)(NBINS + 1) * 4);
    int* rowptr1 = (int*)alloc((size_t)(NNODES + 1) * 4);
    int* rowptr2 = (int*)alloc((size_t)(NNODES + 1) * 4);
    float* dinv1 = (float*)alloc((size_t)NNODES * 4);
    float* dinv2 = (float*)alloc((size_t)NNODES * 4);
    int* col1    = (int*)alloc((size_t)E1 * 4);
    int* col2    = (int*)alloc((size_t)E2 * 4);
    unsigned short* Wt2 = (unsigned short*)alloc((size_t)256 * DIM * 2);
    unsigned short* Wt3 = (unsigned short*)alloc((size_t)256 * NCLS * 2);
    unsigned char* hs8 = (unsigned char*)alloc((size_t)NNODES * 256);
    unsigned short* gs = (unsigned short*)alloc((size_t)NNODES * 32 * 2);
    unsigned short* hcat = (unsigned short*)alloc((size_t)NNODES * 256 * 2);
    // binned arrays alias hcat (dead before agg12 writes hcat); 19.4MB <= 25.6MB
    unsigned int* binned1 = (unsigned int*)hcat;
    unsigned int* binned2 = binned1 + E1;

    hist2_kernel<<<nb1 + nb2, 256, 0, stream>>>(dst1, E1, nb1, hist1, dst2, E2, nb2, hist2);
    scanrow2_kernel<<<NBINS * 2, 256, 0, stream>>>(hist1, nb1, bs1, hist2, nb2, bs2);
    scanbs_kernel<<<2, 256, 0, stream>>>(bs1, bs2);
    scatter2_kernel<<<nb1 + nb2, 256, 0, stream>>>(src1, dst1, E1, nb1, hist1, bs1, binned1,
                                                   src2, dst2, E2, nb2, hist2, bs2, binned2);
    binfill2_kernel<<<NBINS * 2, 256, 0, stream>>>(binned1, bs1, rowptr1, dinv1, col1, E1,
                                                   binned2, bs2, rowptr2, dinv2, col2, E2);

    convW_kernel<<<DIM, 256, 0, stream>>>(W1, W2, Wt2);
    convW3_kernel<<<32, 256, 0, stream>>>(W3, Wt3);
    gemm12_mfma_kernel<<<(NNODES + 63) / 64, 256, 0, stream>>>(x, Wt2, dinv1, dinv2, hs8);
    agg12_kernel<<<(AGG_WAVES_G1 + AGG_WAVES_G2) / 4, 256, 0, stream>>>(
        hs8, rowptr1, col1, rowptr2, col2, dinv1, dinv2, b1, b2, E1, E2, hcat);
    gemm3_mfma_kernel<<<(NNODES + 255) / 256, 256, 0, stream>>>(hcat, Wt3, dinv1, gs);
    agg3_kernel<<<A3_WAVES / 4, 256, 0, stream>>>(gs, rowptr1, col1, dinv1, b3, out, E1);
}

// Round 10
// 323.143 us; speedup vs baseline: 1.2126x; 1.1437x over previous
//
#include <hip/hip_runtime.h>

#define NNODES 50000
#define DIM 512
#define HID 128
#define NCLS 32
#define NBINS 196          // ceil(50000 / 256), bin = dst >> 8
#define CHUNK 8192         // edges per block in hist/scatter passes
#define AGG_WAVES_G1 2048
#define AGG_WAVES_G2 4096
#define A3_WAVES 4096
#define HS_SCALE 64.0f
#define HS_ISCALE 0.015625f

typedef __attribute__((ext_vector_type(8))) short bf16x8;
typedef __attribute__((ext_vector_type(4))) float f32x4;
typedef __attribute__((ext_vector_type(2))) float f32x2;

__device__ __forceinline__ unsigned short f2bf(float f) {
    union { float f; unsigned int u; } a; a.f = f;
    unsigned int u = a.u;
    u += 0x7fff + ((u >> 16) & 1);   // round-to-nearest-even
    return (unsigned short)(u >> 16);
}
__device__ __forceinline__ float bf2f(unsigned short h) {
    union { unsigned int u; float f; } a; a.u = ((unsigned int)h) << 16;
    return a.f;
}
// f32 -> fp8 e4m3 (OCP on gfx950), RNE
__device__ __forceinline__ unsigned char f2fp8(float f) {
    int p = __builtin_amdgcn_cvt_pk_fp8_f32(f, 0.f, 0, false);
    return (unsigned char)(p & 0xff);
}
// 4 packed fp8 -> two f32x2 accumulators (v_pk_add_f32)
__device__ __forceinline__ void fp8add2(unsigned int u, f32x2& a01, f32x2& a23) {
    a01 += __builtin_amdgcn_cvt_pk_f32_fp8((int)u, false);
    a23 += __builtin_amdgcn_cvt_pk_f32_fp8((int)u, true);
}
// min v in [0,NNODES] with rp[v] >= q
__device__ __forceinline__ int lbound(const int* __restrict__ rp, int q) {
    int lo = 0, hi = NNODES;
    while (lo < hi) { int mid = (lo + hi) >> 1; if (rp[mid] >= q) hi = mid; else lo = mid + 1; }
    return lo;
}
// in-place exclusive scan of row[0..n), block of 256; row sum -> *total
__device__ __forceinline__ void scan_inplace(int* __restrict__ row, int n, int* __restrict__ total) {
    __shared__ int wsum[4];
    int tid = threadIdx.x, lane = tid & 63, wid = tid >> 6;
    int base = 0;
    for (int start = 0; start < n; start += 256) {
        int i = start + tid;
        int v = (i < n) ? row[i] : 0;
        int x = v;
        #pragma unroll
        for (int off = 1; off < 64; off <<= 1) {
            int t = __shfl_up(x, off);
            if (lane >= off) x += t;
        }
        if (lane == 63) wsum[wid] = x;
        __syncthreads();
        int woff = 0, tot = 0;
        #pragma unroll
        for (int w = 0; w < 4; ++w) { int s = wsum[w]; if (w < wid) woff += s; tot += s; }
        __syncthreads();
        if (i < n) row[i] = base + woff + x - v;
        base += tot;
    }
    if (tid == 0) *total = base;
}

// ============ deterministic CSR build (merged launches) ============

__global__ __launch_bounds__(256)
void hist2_kernel(const int* __restrict__ dst1, int E1, int nb1, int* __restrict__ hist1,
                  const int* __restrict__ dst2, int E2, int nb2, int* __restrict__ hist2) {
    __shared__ int h[NBINS];
    int blk = blockIdx.x;
    const int* dst; int E, nb, b; int* hist;
    if (blk < nb1) { dst = dst1; E = E1; nb = nb1; b = blk; hist = hist1; }
    else { dst = dst2; E = E2; nb = nb2; b = blk - nb1; hist = hist2; }
    int tid = threadIdx.x;
    for (int i = tid; i < NBINS; i += 256) h[i] = 0;
    __syncthreads();
    int e0 = b * CHUNK;
    int e1 = min(E, e0 + CHUNK);
    for (int e = e0 + tid; e < e1; e += 256)
        atomicAdd(&h[dst[e] >> 8], 1);
    __syncthreads();
    for (int i = tid; i < NBINS; i += 256)
        hist[(size_t)i * nb + b] = h[i];
}

__global__ __launch_bounds__(256)
void scanrow2_kernel(int* __restrict__ hist1, int nb1, int* __restrict__ bs1,
                     int* __restrict__ hist2, int nb2, int* __restrict__ bs2) {
    int b = blockIdx.x;
    if (b < NBINS) scan_inplace(hist1 + (size_t)b * nb1, nb1, bs1 + b);
    else           scan_inplace(hist2 + (size_t)(b - NBINS) * nb2, nb2, bs2 + (b - NBINS));
}

__global__ __launch_bounds__(256)
void scanbs_kernel(int* __restrict__ bs1, int* __restrict__ bs2) {
    if (blockIdx.x == 0) scan_inplace(bs1, NBINS, bs1 + NBINS);
    else                 scan_inplace(bs2, NBINS, bs2 + NBINS);
}

__global__ __launch_bounds__(256)
void scatter2_kernel(const int* __restrict__ src1, const int* __restrict__ dst1, int E1, int nb1,
                     const int* __restrict__ hist1, const int* __restrict__ bs1,
                     unsigned int* __restrict__ binned1,
                     const int* __restrict__ src2, const int* __restrict__ dst2, int E2, int nb2,
                     const int* __restrict__ hist2, const int* __restrict__ bs2,
                     unsigned int* __restrict__ binned2) {
    __shared__ int cur[NBINS];
    int blk = blockIdx.x;
    const int *src, *dst, *hist, *bs; int E, nb, b; unsigned int* binned;
    if (blk < nb1) { src = src1; dst = dst1; E = E1; nb = nb1; b = blk; hist = hist1; bs = bs1; binned = binned1; }
    else { src = src2; dst = dst2; E = E2; nb = nb2; b = blk - nb1; hist = hist2; bs = bs2; binned = binned2; }
    int tid = threadIdx.x;
    for (int i = tid; i < NBINS; i += 256)
        cur[i] = hist[(size_t)i * nb + b] + bs[i];
    __syncthreads();
    int e0 = b * CHUNK;
    int e1 = min(E, e0 + CHUNK);
    for (int e = e0 + tid; e < e1; e += 256) {
        int d = dst[e];
        int bb = d >> 8;
        int p = atomicAdd(&cur[bb], 1);   // LDS atomic only
        binned[p] = ((unsigned int)(d & 255) << 16) | (unsigned int)src[e];
    }
}

// one block per (graph, bin): per-node count -> scan -> rowptr/dinv -> col fill
__global__ __launch_bounds__(256)
void binfill2_kernel(const unsigned int* __restrict__ binned1, const int* __restrict__ bs1,
                     int* __restrict__ rowptr1, float* __restrict__ dinv1,
                     int* __restrict__ col1, int E1,
                     const unsigned int* __restrict__ binned2, const int* __restrict__ bs2,
                     int* __restrict__ rowptr2, float* __restrict__ dinv2,
                     int* __restrict__ col2, int E2) {
    __shared__ int cnt[256], cur[256];
    __shared__ int wsum[4];
    int b = blockIdx.x;
    const unsigned int* binned; const int* bs; int* rowptr; float* dinv; int* col; int totalE;
    if (b < NBINS) { binned = binned1; bs = bs1; rowptr = rowptr1; dinv = dinv1; col = col1; totalE = E1; }
    else { b -= NBINS; binned = binned2; bs = bs2; rowptr = rowptr2; dinv = dinv2; col = col2; totalE = E2; }
    int tid = threadIdx.x, lane = tid & 63, wid = tid >> 6;
    int s = bs[b], e = bs[b + 1];
    cnt[tid] = 0;
    __syncthreads();
    for (int i = s + tid; i < e; i += 256)
        atomicAdd(&cnt[binned[i] >> 16], 1);
    __syncthreads();
    int v = cnt[tid];
    int x = v;
    #pragma unroll
    for (int off = 1; off < 64; off <<= 1) {
        int t = __shfl_up(x, off);
        if (lane >= off) x += t;
    }
    if (lane == 63) wsum[wid] = x;
    __syncthreads();
    int woff = 0;
    #pragma unroll
    for (int w = 0; w < 4; ++w) if (w < wid) woff += wsum[w];
    int ex = woff + x - v;               // exclusive prefix within bin
    cur[tid] = ex;
    __syncthreads();
    int node = b * 256 + tid;
    if (node < NNODES) {
        rowptr[node] = s + ex;
        dinv[node] = rsqrtf((float)v + 1.0f);   // +1 self-loop
    }
    if (b == 0 && tid == 0) rowptr[NNODES] = totalE;
    for (int i = s + tid; i < e; i += 256) {
        unsigned int pk = binned[i];
        int ld = pk >> 16;
        int p = atomicAdd(&cur[ld], 1);  // LDS atomic only
        col[s + p] = (int)(pk & 0xffff);
    }
}

// ---- W permute+cast: Wt2[kt][kg][c][kidx] bf16, c<128 -> W1 col, else W2 col ----

__global__ __launch_bounds__(256)
void convW_kernel(const float* __restrict__ W1, const float* __restrict__ W2,
                  unsigned short* __restrict__ Wt2) {
    int k = blockIdx.x;          // 0..511
    int c = threadIdx.x;         // 0..255
    float v = (c < HID) ? W1[(size_t)k * HID + c] : W2[(size_t)k * HID + (c - HID)];
    int kt = k >> 5, kg = (k >> 3) & 3, kidx = k & 7;
    Wt2[(size_t)kt * 8192 + kg * 2048 + c * 8 + kidx] = f2bf(v);
}

// ---- W3 permute+cast: Wt3[kt][kg][c][kidx] bf16 (k in [0,256), c in [0,32)) ----

__global__ __launch_bounds__(256)
void convW3_kernel(const float* __restrict__ W3, unsigned short* __restrict__ Wt3) {
    int idx = blockIdx.x * 256 + threadIdx.x;   // 0..8191
    int k = idx >> 5, c = idx & 31;
    int kt = k >> 5, kg = (k >> 3) & 3, kidx = k & 7;
    Wt3[(kt * 4 + kg) * 256 + c * 8 + kidx] = f2bf(W3[(size_t)k * NCLS + c]);
}

// ---- MFMA GEMM: hs8[r][c] = fp8(64 * dinv_g[r] * (x@Wg)[r][c]) ----

__global__ __launch_bounds__(256)
void gemm12_mfma_kernel(const float* __restrict__ x, const unsigned short* __restrict__ Wt2,
                        const float* __restrict__ dinv1, const float* __restrict__ dinv2,
                        unsigned char* __restrict__ hs8) {
    __shared__ unsigned short Bs[2][8192];   // 2 x 16KB
    int tid = threadIdx.x;
    int wv = tid >> 6, l = tid & 63;
    int lr = l & 15, lg = l >> 4;
    int m0 = blockIdx.x * 64;
    int row = m0 + wv * 16 + lr;
    int rowc = min(row, NNODES - 1);
    const float* xrow = x + (size_t)rowc * DIM;

    f32x4 acc[16];
    #pragma unroll
    for (int n = 0; n < 16; ++n) acc[n] = (f32x4){0.f, 0.f, 0.f, 0.f};

    uint4 bn[4];
    float4 a0, a1, a0n, a1n;
    #pragma unroll
    for (int p = 0; p < 4; ++p)
        bn[p] = *(const uint4*)(Wt2 + p * 2048 + tid * 8);
    a0 = *(const float4*)(xrow + lg * 8);
    a1 = *(const float4*)(xrow + lg * 8 + 4);
    #pragma unroll
    for (int p = 0; p < 4; ++p)
        *(uint4*)(&Bs[0][p * 2048 + tid * 8]) = bn[p];
    __syncthreads();

    int cur = 0;
    for (int kt = 0; kt < 16; ++kt) {
        if (kt < 15) {
            #pragma unroll
            for (int p = 0; p < 4; ++p)
                bn[p] = *(const uint4*)(Wt2 + (size_t)(kt + 1) * 8192 + p * 2048 + tid * 8);
            a0n = *(const float4*)(xrow + (kt + 1) * 32 + lg * 8);
            a1n = *(const float4*)(xrow + (kt + 1) * 32 + lg * 8 + 4);
        }
        union { bf16x8 v; unsigned short u[8]; } af;
        af.u[0] = f2bf(a0.x); af.u[1] = f2bf(a0.y);
        af.u[2] = f2bf(a0.z); af.u[3] = f2bf(a0.w);
        af.u[4] = f2bf(a1.x); af.u[5] = f2bf(a1.y);
        af.u[6] = f2bf(a1.z); af.u[7] = f2bf(a1.w);
        #pragma unroll
        for (int nf = 0; nf < 16; ++nf) {
            bf16x8 bf = *(const bf16x8*)(&Bs[cur][lg * 2048 + (nf * 16 + lr) * 8]);
            acc[nf] = __builtin_amdgcn_mfma_f32_16x16x32_bf16(af.v, bf, acc[nf], 0, 0, 0);
        }
        if (kt < 15) {
            #pragma unroll
            for (int p = 0; p < 4; ++p)
                *(uint4*)(&Bs[cur ^ 1][p * 2048 + tid * 8]) = bn[p];
            __syncthreads();
            cur ^= 1;
            a0 = a0n; a1 = a1n;
        }
    }

    int row0 = m0 + wv * 16 + lg * 4;
    float d1[4], d2[4];
    #pragma unroll
    for (int j = 0; j < 4; ++j) {
        bool ok = (row0 + j) < NNODES;
        d1[j] = ok ? dinv1[row0 + j] * HS_SCALE : 0.f;
        d2[j] = ok ? dinv2[row0 + j] * HS_SCALE : 0.f;
    }
    #pragma unroll
    for (int nf = 0; nf < 16; ++nf) {
        int c = nf * 16 + lr;
        const float* d = (nf < 8) ? d1 : d2;
        #pragma unroll
        for (int j = 0; j < 4; ++j) {
            int r = row0 + j;
            if (r < NNODES)
                hs8[(size_t)r * 256 + c] = f2fp8(acc[nf][j] * d[j]);
        }
    }
}

// ---- aggregate layers 1&2 (r7-verified form: edge-balanced, quarter/uint2) ----

__global__ __launch_bounds__(256)
void agg12_kernel(const unsigned char* __restrict__ hs8,
                  const int* __restrict__ rowptr1, const int* __restrict__ col1,
                  const int* __restrict__ rowptr2, const int* __restrict__ col2,
                  const float* __restrict__ dinv1, const float* __restrict__ dinv2,
                  const float* __restrict__ b1, const float* __restrict__ b2,
                  int E1, int E2, unsigned short* __restrict__ hcat) {
    int gw = blockIdx.x * 4 + (threadIdx.x >> 6);
    int lane = threadIdx.x & 63;
    int g, w, W; long long E;
    const int *rowptr, *col; const float *dinv, *bias;
    if (gw < AGG_WAVES_G1) {
        g = 0; w = gw; W = AGG_WAVES_G1; E = E1;
        rowptr = rowptr1; col = col1; dinv = dinv1; bias = b1;
    } else {
        g = 1; w = gw - AGG_WAVES_G1; W = AGG_WAVES_G2; E = E2;
        rowptr = rowptr2; col = col2; dinv = dinv2; bias = b2;
    }
    int q0 = (int)(E * w / W);
    int q1 = (int)(E * (w + 1) / W);
    int v0 = lbound(rowptr, q0);
    int v1 = (w == W - 1) ? NNODES : lbound(rowptr, q1);

    int quarter = lane >> 4;       // 0..3 -> edge slot
    int lc = lane & 15;            // col group (8 fp8 each)
    float bias8[8];
    #pragma unroll
    for (int j = 0; j < 8; ++j) bias8[j] = bias[lc * 8 + j];
    const unsigned char* hsg = hs8 + g * 128;

    for (int v = v0; v < v1; ++v) {
        int e0 = rowptr[v], e1 = rowptr[v + 1];
        f32x2 acc[4];
        #pragma unroll
        for (int i = 0; i < 4; ++i) acc[i] = (f32x2){0.f, 0.f};
        int e = e0;
        #pragma unroll 2
        for (; e + 8 <= e1; e += 8) {
            int sA = col[e + quarter];
            int sB = col[e + 4 + quarter];
            uint2 uA = *(const uint2*)(hsg + (size_t)sA * 256 + lc * 8);
            uint2 uB = *(const uint2*)(hsg + (size_t)sB * 256 + lc * 8);
            fp8add2(uA.x, acc[0], acc[1]); fp8add2(uA.y, acc[2], acc[3]);
            fp8add2(uB.x, acc[0], acc[1]); fp8add2(uB.y, acc[2], acc[3]);
        }
        if (e + 4 <= e1) {
            int sA = col[e + quarter];
            uint2 uA = *(const uint2*)(hsg + (size_t)sA * 256 + lc * 8);
            fp8add2(uA.x, acc[0], acc[1]); fp8add2(uA.y, acc[2], acc[3]);
            e += 4;
        }
        if (e < e1 && quarter < e1 - e) {
            int sA = col[e + quarter];
            uint2 uA = *(const uint2*)(hsg + (size_t)sA * 256 + lc * 8);
            fp8add2(uA.x, acc[0], acc[1]); fp8add2(uA.y, acc[2], acc[3]);
        }
        #pragma unroll
        for (int i = 0; i < 4; ++i) {
            #pragma unroll
            for (int off = 16; off <= 32; off <<= 1) {
                acc[i][0] += __shfl_xor(acc[i][0], off);
                acc[i][1] += __shfl_xor(acc[i][1], off);
            }
        }
        uint2 su = *(const uint2*)(hsg + (size_t)v * 256 + lc * 8);
        fp8add2(su.x, acc[0], acc[1]); fp8add2(su.y, acc[2], acc[3]);
        float sc = dinv[v] * HS_ISCALE;
        if (quarter == 0) {
            unsigned int res[4];
            #pragma unroll
            for (int p = 0; p < 4; ++p) {
                float r0 = fmaxf(acc[p][0] * sc + bias8[2 * p + 0], 0.f);
                float r1 = fmaxf(acc[p][1] * sc + bias8[2 * p + 1], 0.f);
                res[p] = (unsigned int)f2bf(r0) | ((unsigned int)f2bf(r1) << 16);
            }
            uint4 st = {res[0], res[1], res[2], res[3]};
            *(uint4*)(hcat + (size_t)v * 256 + g * 128 + lc * 8) = st;
        }
    }
}

// ---- layer-3 MFMA GEMM: gs = bf16(dinv1 * (hcat @ W3)) ----

__global__ __launch_bounds__(256)
void gemm3_mfma_kernel(const unsigned short* __restrict__ hcat,
                       const unsigned short* __restrict__ Wt3,
                       const float* __restrict__ dinv1, unsigned short* __restrict__ gs) {
    __shared__ unsigned short Ws[8192];   // [kt*4+kg][c][8] = 16KB
    int tid = threadIdx.x;
    #pragma unroll
    for (int p = 0; p < 4; ++p)
        *(uint4*)(&Ws[p * 2048 + tid * 8]) = *(const uint4*)(Wt3 + p * 2048 + tid * 8);
    __syncthreads();

    int wv = tid >> 6, l = tid & 63;
    int lr = l & 15, lg = l >> 4;
    int rbase = blockIdx.x * 256 + wv * 64;

    f32x4 acc[4][2];
    #pragma unroll
    for (int m = 0; m < 4; ++m)
        #pragma unroll
        for (int n = 0; n < 2; ++n)
            acc[m][n] = (f32x4){0.f, 0.f, 0.f, 0.f};

    #pragma unroll
    for (int kt = 0; kt < 8; ++kt) {
        #pragma unroll
        for (int m = 0; m < 4; ++m) {
            int rA = min(rbase + m * 16 + lr, NNODES - 1);
            bf16x8 af = *(const bf16x8*)(hcat + (size_t)rA * 256 + kt * 32 + lg * 8);
            #pragma unroll
            for (int n = 0; n < 2; ++n) {
                bf16x8 bf = *(const bf16x8*)(&Ws[(kt * 4 + lg) * 256 + (n * 16 + lr) * 8]);
                acc[m][n] = __builtin_amdgcn_mfma_f32_16x16x32_bf16(af, bf, acc[m][n], 0, 0, 0);
            }
        }
    }

    #pragma unroll
    for (int m = 0; m < 4; ++m) {
        int row0 = rbase + m * 16 + lg * 4;
        float d[4];
        #pragma unroll
        for (int j = 0; j < 4; ++j)
            d[j] = (row0 + j < NNODES) ? dinv1[row0 + j] : 0.f;
        #pragma unroll
        for (int n = 0; n < 2; ++n) {
            int c = n * 16 + lr;
            #pragma unroll
            for (int j = 0; j < 4; ++j) {
                int r = row0 + j;
                if (r < NNODES)
                    gs[(size_t)r * 32 + c] = f2bf(acc[m][n][j] * d[j]);
            }
        }
    }
}

// ---- layer-3 aggregation + bias + log_softmax (edge-balanced, gs bf16) ----

__global__ __launch_bounds__(256)
void agg3_kernel(const unsigned short* __restrict__ gs, const int* __restrict__ rowptr1,
                 const int* __restrict__ col1, const float* __restrict__ dinv1,
                 const float* __restrict__ b3, float* __restrict__ out, int E1) {
    int gw = blockIdx.x * 4 + (threadIdx.x >> 6);
    int lane = threadIdx.x & 63;
    long long E = E1;
    int q0 = (int)(E * gw / A3_WAVES);
    int q1 = (int)(E * (gw + 1) / A3_WAVES);
    int v0 = lbound(rowptr1, q0);
    int v1 = (gw == A3_WAVES - 1) ? NNODES : lbound(rowptr1, q1);

    int oct = lane >> 3;         // 0..7 -> edge slot
    int lc = lane & 7;           // col group (4 vals each)
    float4 b3v = *(const float4*)(b3 + lc * 4);

    for (int v = v0; v < v1; ++v) {
        int e0 = rowptr1[v], e1 = rowptr1[v + 1];
        float a0 = 0.f, a1 = 0.f, a2 = 0.f, a3 = 0.f;
        int e = e0;
        #pragma unroll 2
        for (; e + 8 <= e1; e += 8) {
            int srco = col1[e + oct];
            uint2 u = *(const uint2*)(gs + (size_t)srco * 32 + lc * 4);
            a0 += bf2f((unsigned short)(u.x & 0xffff));
            a1 += bf2f((unsigned short)(u.x >> 16));
            a2 += bf2f((unsigned short)(u.y & 0xffff));
            a3 += bf2f((unsigned short)(u.y >> 16));
        }
        if (e < e1) {
            int r = e1 - e;
            if (oct < r) {
                int srco = col1[e + oct];
                uint2 u = *(const uint2*)(gs + (size_t)srco * 32 + lc * 4);
                a0 += bf2f((unsigned short)(u.x & 0xffff));
                a1 += bf2f((unsigned short)(u.x >> 16));
                a2 += bf2f((unsigned short)(u.y & 0xffff));
                a3 += bf2f((unsigned short)(u.y >> 16));
            }
        }
        #pragma unroll
        for (int off = 32; off >= 8; off >>= 1) {
            a0 += __shfl_xor(a0, off); a1 += __shfl_xor(a1, off);
            a2 += __shfl_xor(a2, off); a3 += __shfl_xor(a3, off);
        }
        uint2 su = *(const uint2*)(gs + (size_t)v * 32 + lc * 4);
        a0 += bf2f((unsigned short)(su.x & 0xffff));
        a1 += bf2f((unsigned short)(su.x >> 16));
        a2 += bf2f((unsigned short)(su.y & 0xffff));
        a3 += bf2f((unsigned short)(su.y >> 16));
        float d = dinv1[v];
        float l0 = a0 * d + b3v.x, l1 = a1 * d + b3v.y;
        float l2 = a2 * d + b3v.z, l3 = a3 * d + b3v.w;
        float m = fmaxf(fmaxf(l0, l1), fmaxf(l2, l3));
        #pragma unroll
        for (int off = 1; off <= 4; off <<= 1) m = fmaxf(m, __shfl_xor(m, off));
        float s = expf(l0 - m) + expf(l1 - m) + expf(l2 - m) + expf(l3 - m);
        #pragma unroll
        for (int off = 1; off <= 4; off <<= 1) s += __shfl_xor(s, off);
        float lg = logf(s);
        if (oct == 0) {
            float4 o = make_float4(l0 - m - lg, l1 - m - lg, l2 - m - lg, l3 - m - lg);
            *(float4*)(out + (size_t)v * 32 + lc * 4) = o;
        }
    }
}

extern "C" void kernel_launch(void* const* d_in, const int* in_sizes, int n_in,
                              void* d_out, int out_size, void* d_ws, size_t ws_size,
                              hipStream_t stream) {
    const float* x  = (const float*)d_in[0];
    const int* ei1  = (const int*)d_in[1];
    const int* ei2  = (const int*)d_in[2];
    const float* W1 = (const float*)d_in[3];
    const float* b1 = (const float*)d_in[4];
    const float* W2 = (const float*)d_in[5];
    const float* b2 = (const float*)d_in[6];
    const float* W3 = (const float*)d_in[7];
    const float* b3 = (const float*)d_in[8];
    float* out = (float*)d_out;

    int E1 = in_sizes[1] / 2;
    int E2 = in_sizes[2] / 2;
    const int* src1 = ei1;       const int* dst1 = ei1 + E1;
    const int* src2 = ei2;       const int* dst2 = ei2 + E2;
    int nb1 = (E1 + CHUNK - 1) / CHUNK;
    int nb2 = (E2 + CHUNK - 1) / CHUNK;

    char* w = (char*)d_ws;
    auto alloc = [&](size_t bytes) -> char* {
        char* p = w; w += (bytes + 255) & ~(size_t)255; return p;
    };
    int* hist1   = (int*)alloc((size_t)NBINS * nb1 * 4);
    int* hist2   = (int*)alloc((size_t)NBINS * nb2 * 4);
    int* bs1     = (int*)alloc((size_t)(NBINS + 1) * 4);
    int* bs2     = (int*)alloc((size_t)(NBINS + 1) * 4);
    int* rowptr1 = (int*)alloc((size_t)(NNODES + 1) * 4);
    int* rowptr2 = (int*)alloc((size_t)(NNODES + 1) * 4);
    float* dinv1 = (float*)alloc((size_t)NNODES * 4);
    float* dinv2 = (float*)alloc((size_t)NNODES * 4);
    int* col1    = (int*)alloc((size_t)E1 * 4);
    int* col2    = (int*)alloc((size_t)E2 * 4);
    unsigned short* Wt2 = (unsigned short*)alloc((size_t)256 * DIM * 2);
    unsigned short* Wt3 = (unsigned short*)alloc((size_t)256 * NCLS * 2);
    unsigned char* hs8 = (unsigned char*)alloc((size_t)NNODES * 256);
    unsigned short* gs = (unsigned short*)alloc((size_t)NNODES * 32 * 2);
    unsigned short* hcat = (unsigned short*)alloc((size_t)NNODES * 256 * 2);
    // binned arrays alias hcat (dead before agg12 writes hcat); 19.4MB <= 25.6MB
    unsigned int* binned1 = (unsigned int*)hcat;
    unsigned int* binned2 = binned1 + E1;

    hist2_kernel<<<nb1 + nb2, 256, 0, stream>>>(dst1, E1, nb1, hist1, dst2, E2, nb2, hist2);
    scanrow2_kernel<<<NBINS * 2, 256, 0, stream>>>(hist1, nb1, bs1, hist2, nb2, bs2);
    scanbs_kernel<<<2, 256, 0, stream>>>(bs1, bs2);
    scatter2_kernel<<<nb1 + nb2, 256, 0, stream>>>(src1, dst1, E1, nb1, hist1, bs1, binned1,
                                                   src2, dst2, E2, nb2, hist2, bs2, binned2);
    binfill2_kernel<<<NBINS * 2, 256, 0, stream>>>(binned1, bs1, rowptr1, dinv1, col1, E1,
                                                   binned2, bs2, rowptr2, dinv2, col2, E2);

    convW_kernel<<<DIM, 256, 0, stream>>>(W1, W2, Wt2);
    convW3_kernel<<<32, 256, 0, stream>>>(W3, Wt3);
    gemm12_mfma_kernel<<<(NNODES + 63) / 64, 256, 0, stream>>>(x, Wt2, dinv1, dinv2, hs8);
    agg12_kernel<<<(AGG_WAVES_G1 + AGG_WAVES_G2) / 4, 256, 0, stream>>>(
        hs8, rowptr1, col1, rowptr2, col2, dinv1, dinv2, b1, b2, E1, E2, hcat);
    gemm3_mfma_kernel<<<(NNODES + 255) / 256, 256, 0, stream>>>(hcat, Wt3, dinv1, gs);
    agg3_kernel<<<A3_WAVES / 4, 256, 0, stream>>>(gs, rowptr1, col1, dinv1, b3, out, E1);
}

// Round 11
// 318.992 us; speedup vs baseline: 1.2284x; 1.0130x over previous
//
#include <hip/hip_runtime.h>

#define NNODES 50000
#define DIM 512
#define HID 128
#define NCLS 32
#define NBINS 196          // ceil(50000 / 256), bin = dst >> 8
#define CHUNK 8192         // edges per block in hist/scatter passes
#define AGG_WAVES_G1 2728
#define AGG_WAVES_G2 5464
#define A3_WAVES 4096
#define HS_SCALE 64.0f
#define HS_ISCALE 0.015625f

typedef __attribute__((ext_vector_type(8))) short bf16x8;
typedef __attribute__((ext_vector_type(4))) float f32x4;
typedef __attribute__((ext_vector_type(2))) float f32x2;

__device__ __forceinline__ unsigned short f2bf(float f) {
    union { float f; unsigned int u; } a; a.f = f;
    unsigned int u = a.u;
    u += 0x7fff + ((u >> 16) & 1);   // round-to-nearest-even
    return (unsigned short)(u >> 16);
}
__device__ __forceinline__ float bf2f(unsigned short h) {
    union { unsigned int u; float f; } a; a.u = ((unsigned int)h) << 16;
    return a.f;
}
// f32 -> fp8 e4m3 (OCP on gfx950), RNE
__device__ __forceinline__ unsigned char f2fp8(float f) {
    int p = __builtin_amdgcn_cvt_pk_fp8_f32(f, 0.f, 0, false);
    return (unsigned char)(p & 0xff);
}
// 4 packed fp8 -> two f32x2 accumulators (v_pk_add_f32)
__device__ __forceinline__ void fp8add2(unsigned int u, f32x2& a01, f32x2& a23) {
    a01 += __builtin_amdgcn_cvt_pk_f32_fp8((int)u, false);
    a23 += __builtin_amdgcn_cvt_pk_f32_fp8((int)u, true);
}
// min v in [0,NNODES] with rp[v] >= q
__device__ __forceinline__ int lbound(const int* __restrict__ rp, int q) {
    int lo = 0, hi = NNODES;
    while (lo < hi) { int mid = (lo + hi) >> 1; if (rp[mid] >= q) hi = mid; else lo = mid + 1; }
    return lo;
}
// in-place exclusive scan of row[0..n), block of 256; row sum -> *total
__device__ __forceinline__ void scan_inplace(int* __restrict__ row, int n, int* __restrict__ total) {
    __shared__ int wsum[4];
    int tid = threadIdx.x, lane = tid & 63, wid = tid >> 6;
    int base = 0;
    for (int start = 0; start < n; start += 256) {
        int i = start + tid;
        int v = (i < n) ? row[i] : 0;
        int x = v;
        #pragma unroll
        for (int off = 1; off < 64; off <<= 1) {
            int t = __shfl_up(x, off);
            if (lane >= off) x += t;
        }
        if (lane == 63) wsum[wid] = x;
        __syncthreads();
        int woff = 0, tot = 0;
        #pragma unroll
        for (int w = 0; w < 4; ++w) { int s = wsum[w]; if (w < wid) woff += s; tot += s; }
        __syncthreads();
        if (i < n) row[i] = base + woff + x - v;
        base += tot;
    }
    if (tid == 0) *total = base;
}

// ============ deterministic CSR build (merged launches) ============

__global__ __launch_bounds__(256)
void hist2_kernel(const int* __restrict__ dst1, int E1, int nb1, int* __restrict__ hist1,
                  const int* __restrict__ dst2, int E2, int nb2, int* __restrict__ hist2) {
    __shared__ int h[NBINS];
    int blk = blockIdx.x;
    const int* dst; int E, nb, b; int* hist;
    if (blk < nb1) { dst = dst1; E = E1; nb = nb1; b = blk; hist = hist1; }
    else { dst = dst2; E = E2; nb = nb2; b = blk - nb1; hist = hist2; }
    int tid = threadIdx.x;
    for (int i = tid; i < NBINS; i += 256) h[i] = 0;
    __syncthreads();
    int e0 = b * CHUNK;
    int e1 = min(E, e0 + CHUNK);
    for (int e = e0 + tid; e < e1; e += 256)
        atomicAdd(&h[dst[e] >> 8], 1);
    __syncthreads();
    for (int i = tid; i < NBINS; i += 256)
        hist[(size_t)i * nb + b] = h[i];
}

__global__ __launch_bounds__(256)
void scanrow2_kernel(int* __restrict__ hist1, int nb1, int* __restrict__ bs1,
                     int* __restrict__ hist2, int nb2, int* __restrict__ bs2) {
    int b = blockIdx.x;
    if (b < NBINS) scan_inplace(hist1 + (size_t)b * nb1, nb1, bs1 + b);
    else           scan_inplace(hist2 + (size_t)(b - NBINS) * nb2, nb2, bs2 + (b - NBINS));
}

__global__ __launch_bounds__(256)
void scanbs_kernel(int* __restrict__ bs1, int* __restrict__ bs2) {
    if (blockIdx.x == 0) scan_inplace(bs1, NBINS, bs1 + NBINS);
    else                 scan_inplace(bs2, NBINS, bs2 + NBINS);
}

__global__ __launch_bounds__(256)
void scatter2_kernel(const int* __restrict__ src1, const int* __restrict__ dst1, int E1, int nb1,
                     const int* __restrict__ hist1, const int* __restrict__ bs1,
                     unsigned int* __restrict__ binned1,
                     const int* __restrict__ src2, const int* __restrict__ dst2, int E2, int nb2,
                     const int* __restrict__ hist2, const int* __restrict__ bs2,
                     unsigned int* __restrict__ binned2) {
    __shared__ int cur[NBINS];
    int blk = blockIdx.x;
    const int *src, *dst, *hist, *bs; int E, nb, b; unsigned int* binned;
    if (blk < nb1) { src = src1; dst = dst1; E = E1; nb = nb1; b = blk; hist = hist1; bs = bs1; binned = binned1; }
    else { src = src2; dst = dst2; E = E2; nb = nb2; b = blk - nb1; hist = hist2; bs = bs2; binned = binned2; }
    int tid = threadIdx.x;
    for (int i = tid; i < NBINS; i += 256)
        cur[i] = hist[(size_t)i * nb + b] + bs[i];
    __syncthreads();
    int e0 = b * CHUNK;
    int e1 = min(E, e0 + CHUNK);
    for (int e = e0 + tid; e < e1; e += 256) {
        int d = dst[e];
        int bb = d >> 8;
        int p = atomicAdd(&cur[bb], 1);   // LDS atomic only
        binned[p] = ((unsigned int)(d & 255) << 16) | (unsigned int)src[e];
    }
}

// one block per (graph, bin): per-node count -> scan -> rowptr/dinv -> col fill
__global__ __launch_bounds__(256)
void binfill2_kernel(const unsigned int* __restrict__ binned1, const int* __restrict__ bs1,
                     int* __restrict__ rowptr1, float* __restrict__ dinv1,
                     int* __restrict__ col1, int E1,
                     const unsigned int* __restrict__ binned2, const int* __restrict__ bs2,
                     int* __restrict__ rowptr2, float* __restrict__ dinv2,
                     int* __restrict__ col2, int E2) {
    __shared__ int cnt[256], cur[256];
    __shared__ int wsum[4];
    int b = blockIdx.x;
    const unsigned int* binned; const int* bs; int* rowptr; float* dinv; int* col; int totalE;
    if (b < NBINS) { binned = binned1; bs = bs1; rowptr = rowptr1; dinv = dinv1; col = col1; totalE = E1; }
    else { b -= NBINS; binned = binned2; bs = bs2; rowptr = rowptr2; dinv = dinv2; col = col2; totalE = E2; }
    int tid = threadIdx.x, lane = tid & 63, wid = tid >> 6;
    int s = bs[b], e = bs[b + 1];
    cnt[tid] = 0;
    __syncthreads();
    for (int i = s + tid; i < e; i += 256)
        atomicAdd(&cnt[binned[i] >> 16], 1);
    __syncthreads();
    int v = cnt[tid];
    int x = v;
    #pragma unroll
    for (int off = 1; off < 64; off <<= 1) {
        int t = __shfl_up(x, off);
        if (lane >= off) x += t;
    }
    if (lane == 63) wsum[wid] = x;
    __syncthreads();
    int woff = 0;
    #pragma unroll
    for (int w = 0; w < 4; ++w) if (w < wid) woff += wsum[w];
    int ex = woff + x - v;               // exclusive prefix within bin
    cur[tid] = ex;
    __syncthreads();
    int node = b * 256 + tid;
    if (node < NNODES) {
        rowptr[node] = s + ex;
        dinv[node] = rsqrtf((float)v + 1.0f);   // +1 self-loop
    }
    if (b == 0 && tid == 0) rowptr[NNODES] = totalE;
    for (int i = s + tid; i < e; i += 256) {
        unsigned int pk = binned[i];
        int ld = pk >> 16;
        int p = atomicAdd(&cur[ld], 1);  // LDS atomic only
        col[s + p] = (int)(pk & 0xffff);
    }
}

// ---- W permute+cast (fused W1/W2 + W3) ----
// blocks 0..511: Wt2[kt][kg][c][kidx]; blocks 512..543: Wt3

__global__ __launch_bounds__(256)
void convW_kernel(const float* __restrict__ W1, const float* __restrict__ W2,
                  const float* __restrict__ W3,
                  unsigned short* __restrict__ Wt2, unsigned short* __restrict__ Wt3) {
    if (blockIdx.x < DIM) {
        int k = blockIdx.x;          // 0..511
        int c = threadIdx.x;         // 0..255
        float v = (c < HID) ? W1[(size_t)k * HID + c] : W2[(size_t)k * HID + (c - HID)];
        int kt = k >> 5, kg = (k >> 3) & 3, kidx = k & 7;
        Wt2[(size_t)kt * 8192 + kg * 2048 + c * 8 + kidx] = f2bf(v);
    } else {
        int idx = (blockIdx.x - DIM) * 256 + threadIdx.x;   // 0..8191
        int k = idx >> 5, c = idx & 31;
        int kt = k >> 5, kg = (k >> 3) & 3, kidx = k & 7;
        Wt3[(kt * 4 + kg) * 256 + c * 8 + kidx] = f2bf(W3[(size_t)k * NCLS + c]);
    }
}

// ---- MFMA GEMM: hs8[r][c] = fp8(64 * dinv_g[r] * (x@Wg)[r][c]) ----
// B staged via async global_load_lds width=16 (LDS dest linear in tid); A via regs.

__global__ __launch_bounds__(256)
void gemm12_mfma_kernel(const float* __restrict__ x, const unsigned short* __restrict__ Wt2,
                        const float* __restrict__ dinv1, const float* __restrict__ dinv2,
                        unsigned char* __restrict__ hs8) {
    __shared__ unsigned short Bs[2][8192];   // 2 x 16KB
    int tid = threadIdx.x;
    int wv = tid >> 6, l = tid & 63;
    int lr = l & 15, lg = l >> 4;
    int m0 = blockIdx.x * 64;
    int row = m0 + wv * 16 + lr;
    int rowc = min(row, NNODES - 1);
    const float* xrow = x + (size_t)rowc * DIM;

    f32x4 acc[16];
    #pragma unroll
    for (int n = 0; n < 16; ++n) acc[n] = (f32x4){0.f, 0.f, 0.f, 0.f};

    // async stage of B tile kt into buffer buf (16B per thread per part)
    auto stage = [&](int kt, int buf) {
        const unsigned short* srcb = Wt2 + (size_t)kt * 8192 + tid * 8;
        #pragma unroll
        for (int p = 0; p < 4; ++p) {
            __builtin_amdgcn_global_load_lds(
                (const __attribute__((address_space(1))) unsigned int*)(const void*)(srcb + p * 2048),
                (__attribute__((address_space(3))) unsigned int*)(void*)(&Bs[buf][p * 2048 + tid * 8]),
                16, 0, 0);
        }
    };

    float4 a0, a1, a0n, a1n;
    stage(0, 0);
    a0 = *(const float4*)(xrow + lg * 8);
    a1 = *(const float4*)(xrow + lg * 8 + 4);
    __syncthreads();   // drains vmcnt: Bs[0] ready

    for (int kt = 0; kt < 16; ++kt) {
        if (kt < 15) {   // stage next B tile (other buffer) + prefetch next A
            stage(kt + 1, (kt + 1) & 1);
            a0n = *(const float4*)(xrow + (kt + 1) * 32 + lg * 8);
            a1n = *(const float4*)(xrow + (kt + 1) * 32 + lg * 8 + 4);
        }
        union { bf16x8 v; unsigned short u[8]; } af;
        af.u[0] = f2bf(a0.x); af.u[1] = f2bf(a0.y);
        af.u[2] = f2bf(a0.z); af.u[3] = f2bf(a0.w);
        af.u[4] = f2bf(a1.x); af.u[5] = f2bf(a1.y);
        af.u[6] = f2bf(a1.z); af.u[7] = f2bf(a1.w);
        #pragma unroll
        for (int nf = 0; nf < 16; ++nf) {
            bf16x8 bf = *(const bf16x8*)(&Bs[kt & 1][lg * 2048 + (nf * 16 + lr) * 8]);
            acc[nf] = __builtin_amdgcn_mfma_f32_16x16x32_bf16(af.v, bf, acc[nf], 0, 0, 0);
        }
        if (kt < 15) {
            __syncthreads();   // drains staging of kt+1; protects Bs[kt&1] overwrite at kt+1
            a0 = a0n; a1 = a1n;
        }
    }

    int row0 = m0 + wv * 16 + lg * 4;
    float d1[4], d2[4];
    #pragma unroll
    for (int j = 0; j < 4; ++j) {
        bool ok = (row0 + j) < NNODES;
        d1[j] = ok ? dinv1[row0 + j] * HS_SCALE : 0.f;
        d2[j] = ok ? dinv2[row0 + j] * HS_SCALE : 0.f;
    }
    #pragma unroll
    for (int nf = 0; nf < 16; ++nf) {
        int c = nf * 16 + lr;
        const float* d = (nf < 8) ? d1 : d2;
        #pragma unroll
        for (int j = 0; j < 4; ++j) {
            int r = row0 + j;
            if (r < NNODES)
                hs8[(size_t)r * 256 + c] = f2fp8(acc[nf][j] * d[j]);
        }
    }
}

// ---- aggregate layers 1&2 (r7-verified form: edge-balanced, quarter/uint2) ----

__global__ __launch_bounds__(256)
void agg12_kernel(const unsigned char* __restrict__ hs8,
                  const int* __restrict__ rowptr1, const int* __restrict__ col1,
                  const int* __restrict__ rowptr2, const int* __restrict__ col2,
                  const float* __restrict__ dinv1, const float* __restrict__ dinv2,
                  const float* __restrict__ b1, const float* __restrict__ b2,
                  int E1, int E2, unsigned short* __restrict__ hcat) {
    int gw = blockIdx.x * 4 + (threadIdx.x >> 6);
    int lane = threadIdx.x & 63;
    int g, w, W; long long E;
    const int *rowptr, *col; const float *dinv, *bias;
    if (gw < AGG_WAVES_G1) {
        g = 0; w = gw; W = AGG_WAVES_G1; E = E1;
        rowptr = rowptr1; col = col1; dinv = dinv1; bias = b1;
    } else {
        g = 1; w = gw - AGG_WAVES_G1; W = AGG_WAVES_G2; E = E2;
        rowptr = rowptr2; col = col2; dinv = dinv2; bias = b2;
    }
    int q0 = (int)(E * w / W);
    int q1 = (int)(E * (w + 1) / W);
    int v0 = lbound(rowptr, q0);
    int v1 = (w == W - 1) ? NNODES : lbound(rowptr, q1);

    int quarter = lane >> 4;       // 0..3 -> edge slot
    int lc = lane & 15;            // col group (8 fp8 each)
    float bias8[8];
    #pragma unroll
    for (int j = 0; j < 8; ++j) bias8[j] = bias[lc * 8 + j];
    const unsigned char* hsg = hs8 + g * 128;

    for (int v = v0; v < v1; ++v) {
        int e0 = rowptr[v], e1 = rowptr[v + 1];
        f32x2 acc[4];
        #pragma unroll
        for (int i = 0; i < 4; ++i) acc[i] = (f32x2){0.f, 0.f};
        int e = e0;
        #pragma unroll 2
        for (; e + 8 <= e1; e += 8) {
            int sA = col[e + quarter];
            int sB = col[e + 4 + quarter];
            uint2 uA = *(const uint2*)(hsg + (size_t)sA * 256 + lc * 8);
            uint2 uB = *(const uint2*)(hsg + (size_t)sB * 256 + lc * 8);
            fp8add2(uA.x, acc[0], acc[1]); fp8add2(uA.y, acc[2], acc[3]);
            fp8add2(uB.x, acc[0], acc[1]); fp8add2(uB.y, acc[2], acc[3]);
        }
        if (e + 4 <= e1) {
            int sA = col[e + quarter];
            uint2 uA = *(const uint2*)(hsg + (size_t)sA * 256 + lc * 8);
            fp8add2(uA.x, acc[0], acc[1]); fp8add2(uA.y, acc[2], acc[3]);
            e += 4;
        }
        if (e < e1 && quarter < e1 - e) {
            int sA = col[e + quarter];
            uint2 uA = *(const uint2*)(hsg + (size_t)sA * 256 + lc * 8);
            fp8add2(uA.x, acc[0], acc[1]); fp8add2(uA.y, acc[2], acc[3]);
        }
        #pragma unroll
        for (int i = 0; i < 4; ++i) {
            #pragma unroll
            for (int off = 16; off <= 32; off <<= 1) {
                acc[i][0] += __shfl_xor(acc[i][0], off);
                acc[i][1] += __shfl_xor(acc[i][1], off);
            }
        }
        uint2 su = *(const uint2*)(hsg + (size_t)v * 256 + lc * 8);
        fp8add2(su.x, acc[0], acc[1]); fp8add2(su.y, acc[2], acc[3]);
        float sc = dinv[v] * HS_ISCALE;
        if (quarter == 0) {
            unsigned int res[4];
            #pragma unroll
            for (int p = 0; p < 4; ++p) {
                float r0 = fmaxf(acc[p][0] * sc + bias8[2 * p + 0], 0.f);
                float r1 = fmaxf(acc[p][1] * sc + bias8[2 * p + 1], 0.f);
                res[p] = (unsigned int)f2bf(r0) | ((unsigned int)f2bf(r1) << 16);
            }
            uint4 st = {res[0], res[1], res[2], res[3]};
            *(uint4*)(hcat + (size_t)v * 256 + g * 128 + lc * 8) = st;
        }
    }
}

// ---- layer-3 MFMA GEMM: gs = bf16(dinv1 * (hcat @ W3)) ----

__global__ __launch_bounds__(256)
void gemm3_mfma_kernel(const unsigned short* __restrict__ hcat,
                       const unsigned short* __restrict__ Wt3,
                       const float* __restrict__ dinv1, unsigned short* __restrict__ gs) {
    __shared__ unsigned short Ws[8192];   // [kt*4+kg][c][8] = 16KB
    int tid = threadIdx.x;
    #pragma unroll
    for (int p = 0; p < 4; ++p)
        *(uint4*)(&Ws[p * 2048 + tid * 8]) = *(const uint4*)(Wt3 + p * 2048 + tid * 8);
    __syncthreads();

    int wv = tid >> 6, l = tid & 63;
    int lr = l & 15, lg = l >> 4;
    int rbase = blockIdx.x * 256 + wv * 64;

    f32x4 acc[4][2];
    #pragma unroll
    for (int m = 0; m < 4; ++m)
        #pragma unroll
        for (int n = 0; n < 2; ++n)
            acc[m][n] = (f32x4){0.f, 0.f, 0.f, 0.f};

    #pragma unroll
    for (int kt = 0; kt < 8; ++kt) {
        #pragma unroll
        for (int m = 0; m < 4; ++m) {
            int rA = min(rbase + m * 16 + lr, NNODES - 1);
            bf16x8 af = *(const bf16x8*)(hcat + (size_t)rA * 256 + kt * 32 + lg * 8);
            #pragma unroll
            for (int n = 0; n < 2; ++n) {
                bf16x8 bf = *(const bf16x8*)(&Ws[(kt * 4 + lg) * 256 + (n * 16 + lr) * 8]);
                acc[m][n] = __builtin_amdgcn_mfma_f32_16x16x32_bf16(af, bf, acc[m][n], 0, 0, 0);
            }
        }
    }

    #pragma unroll
    for (int m = 0; m < 4; ++m) {
        int row0 = rbase + m * 16 + lg * 4;
        float d[4];
        #pragma unroll
        for (int j = 0; j < 4; ++j)
            d[j] = (row0 + j < NNODES) ? dinv1[row0 + j] : 0.f;
        #pragma unroll
        for (int n = 0; n < 2; ++n) {
            int c = n * 16 + lr;
            #pragma unroll
            for (int j = 0; j < 4; ++j) {
                int r = row0 + j;
                if (r < NNODES)
                    gs[(size_t)r * 32 + c] = f2bf(acc[m][n][j] * d[j]);
            }
        }
    }
}

// ---- layer-3 aggregation + bias + log_softmax (edge-balanced, gs bf16) ----

__global__ __launch_bounds__(256)
void agg3_kernel(const unsigned short* __restrict__ gs, const int* __restrict__ rowptr1,
                 const int* __restrict__ col1, const float* __restrict__ dinv1,
                 const float* __restrict__ b3, float* __restrict__ out, int E1) {
    int gw = blockIdx.x * 4 + (threadIdx.x >> 6);
    int lane = threadIdx.x & 63;
    long long E = E1;
    int q0 = (int)(E * gw / A3_WAVES);
    int q1 = (int)(E * (gw + 1) / A3_WAVES);
    int v0 = lbound(rowptr1, q0);
    int v1 = (gw == A3_WAVES - 1) ? NNODES : lbound(rowptr1, q1);

    int oct = lane >> 3;         // 0..7 -> edge slot
    int lc = lane & 7;           // col group (4 vals each)
    float4 b3v = *(const float4*)(b3 + lc * 4);

    for (int v = v0; v < v1; ++v) {
        int e0 = rowptr1[v], e1 = rowptr1[v + 1];
        float a0 = 0.f, a1 = 0.f, a2 = 0.f, a3 = 0.f;
        int e = e0;
        #pragma unroll 2
        for (; e + 8 <= e1; e += 8) {
            int srco = col1[e + oct];
            uint2 u = *(const uint2*)(gs + (size_t)srco * 32 + lc * 4);
            a0 += bf2f((unsigned short)(u.x & 0xffff));
            a1 += bf2f((unsigned short)(u.x >> 16));
            a2 += bf2f((unsigned short)(u.y & 0xffff));
            a3 += bf2f((unsigned short)(u.y >> 16));
        }
        if (e < e1) {
            int r = e1 - e;
            if (oct < r) {
                int srco = col1[e + oct];
                uint2 u = *(const uint2*)(gs + (size_t)srco * 32 + lc * 4);
                a0 += bf2f((unsigned short)(u.x & 0xffff));
                a1 += bf2f((unsigned short)(u.x >> 16));
                a2 += bf2f((unsigned short)(u.y & 0xffff));
                a3 += bf2f((unsigned short)(u.y >> 16));
            }
        }
        #pragma unroll
        for (int off = 32; off >= 8; off >>= 1) {
            a0 += __shfl_xor(a0, off); a1 += __shfl_xor(a1, off);
            a2 += __shfl_xor(a2, off); a3 += __shfl_xor(a3, off);
        }
        uint2 su = *(const uint2*)(gs + (size_t)v * 32 + lc * 4);
        a0 += bf2f((unsigned short)(su.x & 0xffff));
        a1 += bf2f((unsigned short)(su.x >> 16));
        a2 += bf2f((unsigned short)(su.y & 0xffff));
        a3 += bf2f((unsigned short)(su.y >> 16));
        float d = dinv1[v];
        float l0 = a0 * d + b3v.x, l1 = a1 * d + b3v.y;
        float l2 = a2 * d + b3v.z, l3 = a3 * d + b3v.w;
        float m = fmaxf(fmaxf(l0, l1), fmaxf(l2, l3));
        #pragma unroll
        for (int off = 1; off <= 4; off <<= 1) m = fmaxf(m, __shfl_xor(m, off));
        float s = expf(l0 - m) + expf(l1 - m) + expf(l2 - m) + expf(l3 - m);
        #pragma unroll
        for (int off = 1; off <= 4; off <<= 1) s += __shfl_xor(s, off);
        float lg = logf(s);
        if (oct == 0) {
            float4 o = make_float4(l0 - m - lg, l1 - m - lg, l2 - m - lg, l3 - m - lg);
            *(float4*)(out + (size_t)v * 32 + lc * 4) = o;
        }
    }
}

extern "C" void kernel_launch(void* const* d_in, const int* in_sizes, int n_in,
                              void* d_out, int out_size, void* d_ws, size_t ws_size,
                              hipStream_t stream) {
    const float* x  = (const float*)d_in[0];
    const int* ei1  = (const int*)d_in[1];
    const int* ei2  = (const int*)d_in[2];
    const float* W1 = (const float*)d_in[3];
    const float* b1 = (const float*)d_in[4];
    const float* W2 = (const float*)d_in[5];
    const float* b2 = (const float*)d_in[6];
    const float* W3 = (const float*)d_in[7];
    const float* b3 = (const float*)d_in[8];
    float* out = (float*)d_out;

    int E1 = in_sizes[1] / 2;
    int E2 = in_sizes[2] / 2;
    const int* src1 = ei1;       const int* dst1 = ei1 + E1;
    const int* src2 = ei2;       const int* dst2 = ei2 + E2;
    int nb1 = (E1 + CHUNK - 1) / CHUNK;
    int nb2 = (E2 + CHUNK - 1) / CHUNK;

    char* w = (char*)d_ws;
    auto alloc = [&](size_t bytes) -> char* {
        char* p = w; w += (bytes + 255) & ~(size_t)255; return p;
    };
    int* hist1   = (int*)alloc((size_t)NBINS * nb1 * 4);
    int* hist2   = (int*)alloc((size_t)NBINS * nb2 * 4);
    int* bs1     = (int*)alloc((size_t)(NBINS + 1) * 4);
    int* bs2     = (int*)alloc((size_t)(NBINS + 1) * 4);
    int* rowptr1 = (int*)alloc((size_t)(NNODES + 1) * 4);
    int* rowptr2 = (int*)alloc((size_t)(NNODES + 1) * 4);
    float* dinv1 = (float*)alloc((size_t)NNODES * 4);
    float* dinv2 = (float*)alloc((size_t)NNODES * 4);
    int* col1    = (int*)alloc((size_t)E1 * 4);
    int* col2    = (int*)alloc((size_t)E2 * 4);
    unsigned short* Wt2 = (unsigned short*)alloc((size_t)256 * DIM * 2);
    unsigned short* Wt3 = (unsigned short*)alloc((size_t)256 * NCLS * 2);
    unsigned char* hs8 = (unsigned char*)alloc((size_t)NNODES * 256);
    unsigned short* gs = (unsigned short*)alloc((size_t)NNODES * 32 * 2);
    unsigned short* hcat = (unsigned short*)alloc((size_t)NNODES * 256 * 2);
    // binned arrays alias hcat (dead before agg12 writes hcat); 19.4MB <= 25.6MB
    unsigned int* binned1 = (unsigned int*)hcat;
    unsigned int* binned2 = binned1 + E1;

    hist2_kernel<<<nb1 + nb2, 256, 0, stream>>>(dst1, E1, nb1, hist1, dst2, E2, nb2, hist2);
    scanrow2_kernel<<<NBINS * 2, 256, 0, stream>>>(hist1, nb1, bs1, hist2, nb2, bs2);
    scanbs_kernel<<<2, 256, 0, stream>>>(bs1, bs2);
    scatter2_kernel<<<nb1 + nb2, 256, 0, stream>>>(src1, dst1, E1, nb1, hist1, bs1, binned1,
                                                   src2, dst2, E2, nb2, hist2, bs2, binned2);
    binfill2_kernel<<<NBINS * 2, 256, 0, stream>>>(binned1, bs1, rowptr1, dinv1, col1, E1,
                                                   binned2, bs2, rowptr2, dinv2, col2, E2);

    convW_kernel<<<DIM + 32, 256, 0, stream>>>(W1, W2, W3, Wt2, Wt3);
    gemm12_mfma_kernel<<<(NNODES + 63) / 64, 256, 0, stream>>>(x, Wt2, dinv1, dinv2, hs8);
    agg12_kernel<<<(AGG_WAVES_G1 + AGG_WAVES_G2) / 4, 256, 0, stream>>>(
        hs8, rowptr1, col1, rowptr2, col2, dinv1, dinv2, b1, b2, E1, E2, hcat);
    gemm3_mfma_kernel<<<(NNODES + 255) / 256, 256, 0, stream>>>(hcat, Wt3, dinv1, gs);
    agg3_kernel<<<A3_WAVES / 4, 256, 0, stream>>>(gs, rowptr1, col1, dinv1, b3, out, E1);
}

// Round 12
// 295.186 us; speedup vs baseline: 1.3274x; 1.0806x over previous
//
#include <hip/hip_runtime.h>

#define NNODES 50000
#define DIM 512
#define HID 128
#define NCLS 32
#define NBINS 196          // ceil(50000 / 256), bin = dst >> 8
#define CHUNK 8192         // edges per block in hist/scatter passes
#define AGG_WAVES_G1 2048
#define AGG_WAVES_G2 4096
#define A3_WAVES 4096
#define HS_SCALE 64.0f
#define HS_ISCALE 0.015625f

typedef __attribute__((ext_vector_type(8))) short bf16x8;
typedef __attribute__((ext_vector_type(4))) float f32x4;
typedef __attribute__((ext_vector_type(2))) float f32x2;

__device__ __forceinline__ unsigned short f2bf(float f) {
    union { float f; unsigned int u; } a; a.f = f;
    unsigned int u = a.u;
    u += 0x7fff + ((u >> 16) & 1);   // round-to-nearest-even
    return (unsigned short)(u >> 16);
}
__device__ __forceinline__ float bf2f(unsigned short h) {
    union { unsigned int u; float f; } a; a.u = ((unsigned int)h) << 16;
    return a.f;
}
// f32 -> fp8 e4m3 (OCP on gfx950), RNE
__device__ __forceinline__ unsigned char f2fp8(float f) {
    int p = __builtin_amdgcn_cvt_pk_fp8_f32(f, 0.f, 0, false);
    return (unsigned char)(p & 0xff);
}
// 4 packed fp8 -> two f32x2 accumulators (v_pk_add_f32)
__device__ __forceinline__ void fp8add2(unsigned int u, f32x2& a01, f32x2& a23) {
    a01 += __builtin_amdgcn_cvt_pk_f32_fp8((int)u, false);
    a23 += __builtin_amdgcn_cvt_pk_f32_fp8((int)u, true);
}
// min v in [0,NNODES] with rp[v] >= q
__device__ __forceinline__ int lbound(const int* __restrict__ rp, int q) {
    int lo = 0, hi = NNODES;
    while (lo < hi) { int mid = (lo + hi) >> 1; if (rp[mid] >= q) hi = mid; else lo = mid + 1; }
    return lo;
}
// in-place exclusive scan of row[0..n), block of 256; row sum -> *total
__device__ __forceinline__ void scan_inplace(int* __restrict__ row, int n, int* __restrict__ total) {
    __shared__ int wsum[4];
    int tid = threadIdx.x, lane = tid & 63, wid = tid >> 6;
    int base = 0;
    for (int start = 0; start < n; start += 256) {
        int i = start + tid;
        int v = (i < n) ? row[i] : 0;
        int x = v;
        #pragma unroll
        for (int off = 1; off < 64; off <<= 1) {
            int t = __shfl_up(x, off);
            if (lane >= off) x += t;
        }
        if (lane == 63) wsum[wid] = x;
        __syncthreads();
        int woff = 0, tot = 0;
        #pragma unroll
        for (int w = 0; w < 4; ++w) { int s = wsum[w]; if (w < wid) woff += s; tot += s; }
        __syncthreads();
        if (i < n) row[i] = base + woff + x - v;
        base += tot;
    }
    if (tid == 0) *total = base;
}

// ============ deterministic CSR build (merged launches) ============

__global__ __launch_bounds__(256)
void hist2_kernel(const int* __restrict__ dst1, int E1, int nb1, int* __restrict__ hist1,
                  const int* __restrict__ dst2, int E2, int nb2, int* __restrict__ hist2) {
    __shared__ int h[NBINS];
    int blk = blockIdx.x;
    const int* dst; int E, nb, b; int* hist;
    if (blk < nb1) { dst = dst1; E = E1; nb = nb1; b = blk; hist = hist1; }
    else { dst = dst2; E = E2; nb = nb2; b = blk - nb1; hist = hist2; }
    int tid = threadIdx.x;
    for (int i = tid; i < NBINS; i += 256) h[i] = 0;
    __syncthreads();
    int e0 = b * CHUNK;
    int e1 = min(E, e0 + CHUNK);
    for (int e = e0 + tid; e < e1; e += 256)
        atomicAdd(&h[dst[e] >> 8], 1);
    __syncthreads();
    for (int i = tid; i < NBINS; i += 256)
        hist[(size_t)i * nb + b] = h[i];
}

__global__ __launch_bounds__(256)
void scanrow2_kernel(int* __restrict__ hist1, int nb1, int* __restrict__ bs1,
                     int* __restrict__ hist2, int nb2, int* __restrict__ bs2) {
    int b = blockIdx.x;
    if (b < NBINS) scan_inplace(hist1 + (size_t)b * nb1, nb1, bs1 + b);
    else           scan_inplace(hist2 + (size_t)(b - NBINS) * nb2, nb2, bs2 + (b - NBINS));
}

__global__ __launch_bounds__(256)
void scanbs_kernel(int* __restrict__ bs1, int* __restrict__ bs2) {
    if (blockIdx.x == 0) scan_inplace(bs1, NBINS, bs1 + NBINS);
    else                 scan_inplace(bs2, NBINS, bs2 + NBINS);
}

__global__ __launch_bounds__(256)
void scatter2_kernel(const int* __restrict__ src1, const int* __restrict__ dst1, int E1, int nb1,
                     const int* __restrict__ hist1, const int* __restrict__ bs1,
                     unsigned int* __restrict__ binned1,
                     const int* __restrict__ src2, const int* __restrict__ dst2, int E2, int nb2,
                     const int* __restrict__ hist2, const int* __restrict__ bs2,
                     unsigned int* __restrict__ binned2) {
    __shared__ int cur[NBINS];
    int blk = blockIdx.x;
    const int *src, *dst, *hist, *bs; int E, nb, b; unsigned int* binned;
    if (blk < nb1) { src = src1; dst = dst1; E = E1; nb = nb1; b = blk; hist = hist1; bs = bs1; binned = binned1; }
    else { src = src2; dst = dst2; E = E2; nb = nb2; b = blk - nb1; hist = hist2; bs = bs2; binned = binned2; }
    int tid = threadIdx.x;
    for (int i = tid; i < NBINS; i += 256)
        cur[i] = hist[(size_t)i * nb + b] + bs[i];
    __syncthreads();
    int e0 = b * CHUNK;
    int e1 = min(E, e0 + CHUNK);
    for (int e = e0 + tid; e < e1; e += 256) {
        int d = dst[e];
        int bb = d >> 8;
        int p = atomicAdd(&cur[bb], 1);   // LDS atomic only
        binned[p] = ((unsigned int)(d & 255) << 16) | (unsigned int)src[e];
    }
}

// one block per (graph, bin): per-node count -> scan -> rowptr/dinv -> col fill
__global__ __launch_bounds__(256)
void binfill2_kernel(const unsigned int* __restrict__ binned1, const int* __restrict__ bs1,
                     int* __restrict__ rowptr1, float* __restrict__ dinv1,
                     int* __restrict__ col1, int E1,
                     const unsigned int* __restrict__ binned2, const int* __restrict__ bs2,
                     int* __restrict__ rowptr2, float* __restrict__ dinv2,
                     int* __restrict__ col2, int E2) {
    __shared__ int cnt[256], cur[256];
    __shared__ int wsum[4];
    int b = blockIdx.x;
    const unsigned int* binned; const int* bs; int* rowptr; float* dinv; int* col; int totalE;
    if (b < NBINS) { binned = binned1; bs = bs1; rowptr = rowptr1; dinv = dinv1; col = col1; totalE = E1; }
    else { b -= NBINS; binned = binned2; bs = bs2; rowptr = rowptr2; dinv = dinv2; col = col2; totalE = E2; }
    int tid = threadIdx.x, lane = tid & 63, wid = tid >> 6;
    int s = bs[b], e = bs[b + 1];
    cnt[tid] = 0;
    __syncthreads();
    for (int i = s + tid; i < e; i += 256)
        atomicAdd(&cnt[binned[i] >> 16], 1);
    __syncthreads();
    int v = cnt[tid];
    int x = v;
    #pragma unroll
    for (int off = 1; off < 64; off <<= 1) {
        int t = __shfl_up(x, off);
        if (lane >= off) x += t;
    }
    if (lane == 63) wsum[wid] = x;
    __syncthreads();
    int woff = 0;
    #pragma unroll
    for (int w = 0; w < 4; ++w) if (w < wid) woff += wsum[w];
    int ex = woff + x - v;               // exclusive prefix within bin
    cur[tid] = ex;
    __syncthreads();
    int node = b * 256 + tid;
    if (node < NNODES) {
        rowptr[node] = s + ex;
        dinv[node] = rsqrtf((float)v + 1.0f);   // +1 self-loop
    }
    if (b == 0 && tid == 0) rowptr[NNODES] = totalE;
    for (int i = s + tid; i < e; i += 256) {
        unsigned int pk = binned[i];
        int ld = pk >> 16;
        int p = atomicAdd(&cur[ld], 1);  // LDS atomic only
        col[s + p] = (int)(pk & 0xffff);
    }
}

// ---- W permute+cast (fused W1/W2 + W3) ----

__global__ __launch_bounds__(256)
void convW_kernel(const float* __restrict__ W1, const float* __restrict__ W2,
                  const float* __restrict__ W3,
                  unsigned short* __restrict__ Wt2, unsigned short* __restrict__ Wt3) {
    if (blockIdx.x < DIM) {
        int k = blockIdx.x;          // 0..511
        int c = threadIdx.x;         // 0..255
        float v = (c < HID) ? W1[(size_t)k * HID + c] : W2[(size_t)k * HID + (c - HID)];
        int kt = k >> 5, kg = (k >> 3) & 3, kidx = k & 7;
        Wt2[(size_t)kt * 8192 + kg * 2048 + c * 8 + kidx] = f2bf(v);
    } else {
        int idx = (blockIdx.x - DIM) * 256 + threadIdx.x;   // 0..8191
        int k = idx >> 5, c = idx & 31;
        int kt = k >> 5, kg = (k >> 3) & 3, kidx = k & 7;
        Wt3[(kt * 4 + kg) * 256 + c * 8 + kidx] = f2bf(W3[(size_t)k * NCLS + c]);
    }
}

// ---- MFMA GEMM: hs8[r][c] = fp8(64 * dinv_g[r] * (x@Wg)[r][c]) ----
// B staged via async global_load_lds width=16 (LDS dest linear in tid); A via regs.

__global__ __launch_bounds__(256)
void gemm12_mfma_kernel(const float* __restrict__ x, const unsigned short* __restrict__ Wt2,
                        const float* __restrict__ dinv1, const float* __restrict__ dinv2,
                        unsigned char* __restrict__ hs8) {
    __shared__ unsigned short Bs[2][8192];   // 2 x 16KB
    int tid = threadIdx.x;
    int wv = tid >> 6, l = tid & 63;
    int lr = l & 15, lg = l >> 4;
    int m0 = blockIdx.x * 64;
    int row = m0 + wv * 16 + lr;
    int rowc = min(row, NNODES - 1);
    const float* xrow = x + (size_t)rowc * DIM;

    f32x4 acc[16];
    #pragma unroll
    for (int n = 0; n < 16; ++n) acc[n] = (f32x4){0.f, 0.f, 0.f, 0.f};

    // async stage of B tile kt into buffer buf (16B per thread per part)
    auto stage = [&](int kt, int buf) {
        const unsigned short* srcb = Wt2 + (size_t)kt * 8192 + tid * 8;
        #pragma unroll
        for (int p = 0; p < 4; ++p) {
            __builtin_amdgcn_global_load_lds(
                (const __attribute__((address_space(1))) unsigned int*)(const void*)(srcb + p * 2048),
                (__attribute__((address_space(3))) unsigned int*)(void*)(&Bs[buf][p * 2048 + tid * 8]),
                16, 0, 0);
        }
    };

    float4 a0, a1, a0n, a1n;
    stage(0, 0);
    a0 = *(const float4*)(xrow + lg * 8);
    a1 = *(const float4*)(xrow + lg * 8 + 4);
    __syncthreads();   // drains vmcnt: Bs[0] ready

    for (int kt = 0; kt < 16; ++kt) {
        if (kt < 15) {   // stage next B tile (other buffer) + prefetch next A
            stage(kt + 1, (kt + 1) & 1);
            a0n = *(const float4*)(xrow + (kt + 1) * 32 + lg * 8);
            a1n = *(const float4*)(xrow + (kt + 1) * 32 + lg * 8 + 4);
        }
        union { bf16x8 v; unsigned short u[8]; } af;
        af.u[0] = f2bf(a0.x); af.u[1] = f2bf(a0.y);
        af.u[2] = f2bf(a0.z); af.u[3] = f2bf(a0.w);
        af.u[4] = f2bf(a1.x); af.u[5] = f2bf(a1.y);
        af.u[6] = f2bf(a1.z); af.u[7] = f2bf(a1.w);
        #pragma unroll
        for (int nf = 0; nf < 16; ++nf) {
            bf16x8 bf = *(const bf16x8*)(&Bs[kt & 1][lg * 2048 + (nf * 16 + lr) * 8]);
            acc[nf] = __builtin_amdgcn_mfma_f32_16x16x32_bf16(af.v, bf, acc[nf], 0, 0, 0);
        }
        if (kt < 15) {
            __syncthreads();   // drains staging of kt+1; protects Bs[kt&1] overwrite at kt+1
            a0 = a0n; a1 = a1n;
        }
    }

    int row0 = m0 + wv * 16 + lg * 4;
    float d1[4], d2[4];
    #pragma unroll
    for (int j = 0; j < 4; ++j) {
        bool ok = (row0 + j) < NNODES;
        d1[j] = ok ? dinv1[row0 + j] * HS_SCALE : 0.f;
        d2[j] = ok ? dinv2[row0 + j] * HS_SCALE : 0.f;
    }
    #pragma unroll
    for (int nf = 0; nf < 16; ++nf) {
        int c = nf * 16 + lr;
        const float* d = (nf < 8) ? d1 : d2;
        #pragma unroll
        for (int j = 0; j < 4; ++j) {
            int r = row0 + j;
            if (r < NNODES)
                hs8[(size_t)r * 256 + c] = f2fp8(acc[nf][j] * d[j]);
        }
    }
}

// ---- aggregate layers 1&2 (r7-verified form: edge-balanced, quarter/uint2,
//      2048/4096 waves — measured optimum across 3 grid sizes; FROZEN) ----

__global__ __launch_bounds__(256)
void agg12_kernel(const unsigned char* __restrict__ hs8,
                  const int* __restrict__ rowptr1, const int* __restrict__ col1,
                  const int* __restrict__ rowptr2, const int* __restrict__ col2,
                  const float* __restrict__ dinv1, const float* __restrict__ dinv2,
                  const float* __restrict__ b1, const float* __restrict__ b2,
                  int E1, int E2, unsigned short* __restrict__ hcat) {
    int gw = blockIdx.x * 4 + (threadIdx.x >> 6);
    int lane = threadIdx.x & 63;
    int g, w, W; long long E;
    const int *rowptr, *col; const float *dinv, *bias;
    if (gw < AGG_WAVES_G1) {
        g = 0; w = gw; W = AGG_WAVES_G1; E = E1;
        rowptr = rowptr1; col = col1; dinv = dinv1; bias = b1;
    } else {
        g = 1; w = gw - AGG_WAVES_G1; W = AGG_WAVES_G2; E = E2;
        rowptr = rowptr2; col = col2; dinv = dinv2; bias = b2;
    }
    int q0 = (int)(E * w / W);
    int q1 = (int)(E * (w + 1) / W);
    int v0 = lbound(rowptr, q0);
    int v1 = (w == W - 1) ? NNODES : lbound(rowptr, q1);

    int quarter = lane >> 4;       // 0..3 -> edge slot
    int lc = lane & 15;            // col group (8 fp8 each)
    float bias8[8];
    #pragma unroll
    for (int j = 0; j < 8; ++j) bias8[j] = bias[lc * 8 + j];
    const unsigned char* hsg = hs8 + g * 128;

    for (int v = v0; v < v1; ++v) {
        int e0 = rowptr[v], e1 = rowptr[v + 1];
        f32x2 acc[4];
        #pragma unroll
        for (int i = 0; i < 4; ++i) acc[i] = (f32x2){0.f, 0.f};
        int e = e0;
        #pragma unroll 2
        for (; e + 8 <= e1; e += 8) {
            int sA = col[e + quarter];
            int sB = col[e + 4 + quarter];
            uint2 uA = *(const uint2*)(hsg + (size_t)sA * 256 + lc * 8);
            uint2 uB = *(const uint2*)(hsg + (size_t)sB * 256 + lc * 8);
            fp8add2(uA.x, acc[0], acc[1]); fp8add2(uA.y, acc[2], acc[3]);
            fp8add2(uB.x, acc[0], acc[1]); fp8add2(uB.y, acc[2], acc[3]);
        }
        if (e + 4 <= e1) {
            int sA = col[e + quarter];
            uint2 uA = *(const uint2*)(hsg + (size_t)sA * 256 + lc * 8);
            fp8add2(uA.x, acc[0], acc[1]); fp8add2(uA.y, acc[2], acc[3]);
            e += 4;
        }
        if (e < e1 && quarter < e1 - e) {
            int sA = col[e + quarter];
            uint2 uA = *(const uint2*)(hsg + (size_t)sA * 256 + lc * 8);
            fp8add2(uA.x, acc[0], acc[1]); fp8add2(uA.y, acc[2], acc[3]);
        }
        #pragma unroll
        for (int i = 0; i < 4; ++i) {
            #pragma unroll
            for (int off = 16; off <= 32; off <<= 1) {
                acc[i][0] += __shfl_xor(acc[i][0], off);
                acc[i][1] += __shfl_xor(acc[i][1], off);
            }
        }
        uint2 su = *(const uint2*)(hsg + (size_t)v * 256 + lc * 8);
        fp8add2(su.x, acc[0], acc[1]); fp8add2(su.y, acc[2], acc[3]);
        float sc = dinv[v] * HS_ISCALE;
        if (quarter == 0) {
            unsigned int res[4];
            #pragma unroll
            for (int p = 0; p < 4; ++p) {
                float r0 = fmaxf(acc[p][0] * sc + bias8[2 * p + 0], 0.f);
                float r1 = fmaxf(acc[p][1] * sc + bias8[2 * p + 1], 0.f);
                res[p] = (unsigned int)f2bf(r0) | ((unsigned int)f2bf(r1) << 16);
            }
            uint4 st = {res[0], res[1], res[2], res[3]};
            *(uint4*)(hcat + (size_t)v * 256 + g * 128 + lc * 8) = st;
        }
    }
}

// ---- layer-3 MFMA GEMM: gs = bf16(dinv1 * (hcat @ W3)) ----

__global__ __launch_bounds__(256)
void gemm3_mfma_kernel(const unsigned short* __restrict__ hcat,
                       const unsigned short* __restrict__ Wt3,
                       const float* __restrict__ dinv1, unsigned short* __restrict__ gs) {
    __shared__ unsigned short Ws[8192];   // [kt*4+kg][c][8] = 16KB
    int tid = threadIdx.x;
    #pragma unroll
    for (int p = 0; p < 4; ++p)
        *(uint4*)(&Ws[p * 2048 + tid * 8]) = *(const uint4*)(Wt3 + p * 2048 + tid * 8);
    __syncthreads();

    int wv = tid >> 6, l = tid & 63;
    int lr = l & 15, lg = l >> 4;
    int rbase = blockIdx.x * 256 + wv * 64;

    f32x4 acc[4][2];
    #pragma unroll
    for (int m = 0; m < 4; ++m)
        #pragma unroll
        for (int n = 0; n < 2; ++n)
            acc[m][n] = (f32x4){0.f, 0.f, 0.f, 0.f};

    #pragma unroll
    for (int kt = 0; kt < 8; ++kt) {
        #pragma unroll
        for (int m = 0; m < 4; ++m) {
            int rA = min(rbase + m * 16 + lr, NNODES - 1);
            bf16x8 af = *(const bf16x8*)(hcat + (size_t)rA * 256 + kt * 32 + lg * 8);
            #pragma unroll
            for (int n = 0; n < 2; ++n) {
                bf16x8 bf = *(const bf16x8*)(&Ws[(kt * 4 + lg) * 256 + (n * 16 + lr) * 8]);
                acc[m][n] = __builtin_amdgcn_mfma_f32_16x16x32_bf16(af, bf, acc[m][n], 0, 0, 0);
            }
        }
    }

    #pragma unroll
    for (int m = 0; m < 4; ++m) {
        int row0 = rbase + m * 16 + lg * 4;
        float d[4];
        #pragma unroll
        for (int j = 0; j < 4; ++j)
            d[j] = (row0 + j < NNODES) ? dinv1[row0 + j] : 0.f;
        #pragma unroll
        for (int n = 0; n < 2; ++n) {
            int c = n * 16 + lr;
            #pragma unroll
            for (int j = 0; j < 4; ++j) {
                int r = row0 + j;
                if (r < NNODES)
                    gs[(size_t)r * 32 + c] = f2bf(acc[m][n][j] * d[j]);
            }
        }
    }
}

// ---- layer-3 aggregation + bias + log_softmax (edge-balanced, gs bf16) ----

__global__ __launch_bounds__(256)
void agg3_kernel(const unsigned short* __restrict__ gs, const int* __restrict__ rowptr1,
                 const int* __restrict__ col1, const float* __restrict__ dinv1,
                 const float* __restrict__ b3, float* __restrict__ out, int E1) {
    int gw = blockIdx.x * 4 + (threadIdx.x >> 6);
    int lane = threadIdx.x & 63;
    long long E = E1;
    int q0 = (int)(E * gw / A3_WAVES);
    int q1 = (int)(E * (gw + 1) / A3_WAVES);
    int v0 = lbound(rowptr1, q0);
    int v1 = (gw == A3_WAVES - 1) ? NNODES : lbound(rowptr1, q1);

    int oct = lane >> 3;         // 0..7 -> edge slot
    int lc = lane & 7;           // col group (4 vals each)
    float4 b3v = *(const float4*)(b3 + lc * 4);

    for (int v = v0; v < v1; ++v) {
        int e0 = rowptr1[v], e1 = rowptr1[v + 1];
        float a0 = 0.f, a1 = 0.f, a2 = 0.f, a3 = 0.f;
        int e = e0;
        #pragma unroll 2
        for (; e + 8 <= e1; e += 8) {
            int srco = col1[e + oct];
            uint2 u = *(const uint2*)(gs + (size_t)srco * 32 + lc * 4);
            a0 += bf2f((unsigned short)(u.x & 0xffff));
            a1 += bf2f((unsigned short)(u.x >> 16));
            a2 += bf2f((unsigned short)(u.y & 0xffff));
            a3 += bf2f((unsigned short)(u.y >> 16));
        }
        if (e < e1) {
            int r = e1 - e;
            if (oct < r) {
                int srco = col1[e + oct];
                uint2 u = *(const uint2*)(gs + (size_t)srco * 32 + lc * 4);
                a0 += bf2f((unsigned short)(u.x & 0xffff));
                a1 += bf2f((unsigned short)(u.x >> 16));
                a2 += bf2f((unsigned short)(u.y & 0xffff));
                a3 += bf2f((unsigned short)(u.y >> 16));
            }
        }
        #pragma unroll
        for (int off = 32; off >= 8; off >>= 1) {
            a0 += __shfl_xor(a0, off); a1 += __shfl_xor(a1, off);
            a2 += __shfl_xor(a2, off); a3 += __shfl_xor(a3, off);
        }
        uint2 su = *(const uint2*)(gs + (size_t)v * 32 + lc * 4);
        a0 += bf2f((unsigned short)(su.x & 0xffff));
        a1 += bf2f((unsigned short)(su.x >> 16));
        a2 += bf2f((unsigned short)(su.y & 0xffff));
        a3 += bf2f((unsigned short)(su.y >> 16));
        float d = dinv1[v];
        float l0 = a0 * d + b3v.x, l1 = a1 * d + b3v.y;
        float l2 = a2 * d + b3v.z, l3 = a3 * d + b3v.w;
        float m = fmaxf(fmaxf(l0, l1), fmaxf(l2, l3));
        #pragma unroll
        for (int off = 1; off <= 4; off <<= 1) m = fmaxf(m, __shfl_xor(m, off));
        float s = expf(l0 - m) + expf(l1 - m) + expf(l2 - m) + expf(l3 - m);
        #pragma unroll
        for (int off = 1; off <= 4; off <<= 1) s += __shfl_xor(s, off);
        float lg = logf(s);
        if (oct == 0) {
            float4 o = make_float4(l0 - m - lg, l1 - m - lg, l2 - m - lg, l3 - m - lg);
            *(float4*)(out + (size_t)v * 32 + lc * 4) = o;
        }
    }
}

extern "C" void kernel_launch(void* const* d_in, const int* in_sizes, int n_in,
                              void* d_out, int out_size, void* d_ws, size_t ws_size,
                              hipStream_t stream) {
    const float* x  = (const float*)d_in[0];
    const int* ei1  = (const int*)d_in[1];
    const int* ei2  = (const int*)d_in[2];
    const float* W1 = (const float*)d_in[3];
    const float* b1 = (const float*)d_in[4];
    const float* W2 = (const float*)d_in[5];
    const float* b2 = (const float*)d_in[6];
    const float* W3 = (const float*)d_in[7];
    const float* b3 = (const float*)d_in[8];
    float* out = (float*)d_out;

    int E1 = in_sizes[1] / 2;
    int E2 = in_sizes[2] / 2;
    const int* src1 = ei1;       const int* dst1 = ei1 + E1;
    const int* src2 = ei2;       const int* dst2 = ei2 + E2;
    int nb1 = (E1 + CHUNK - 1) / CHUNK;
    int nb2 = (E2 + CHUNK - 1) / CHUNK;

    char* w = (char*)d_ws;
    auto alloc = [&](size_t bytes) -> char* {
        char* p = w; w += (bytes + 255) & ~(size_t)255; return p;
    };
    int* hist1   = (int*)alloc((size_t)NBINS * nb1 * 4);
    int* hist2   = (int*)alloc((size_t)NBINS * nb2 * 4);
    int* bs1     = (int*)alloc((size_t)(NBINS + 1) * 4);
    int* bs2     = (int*)alloc((size_t)(NBINS + 1) * 4);
    int* rowptr1 = (int*)alloc((size_t)(NNODES + 1) * 4);
    int* rowptr2 = (int*)alloc((size_t)(NNODES + 1) * 4);
    float* dinv1 = (float*)alloc((size_t)NNODES * 4);
    float* dinv2 = (float*)alloc((size_t)NNODES * 4);
    int* col1    = (int*)alloc((size_t)E1 * 4);
    int* col2    = (int*)alloc((size_t)E2 * 4);
    unsigned short* Wt2 = (unsigned short*)alloc((size_t)256 * DIM * 2);
    unsigned short* Wt3 = (unsigned short*)alloc((size_t)256 * NCLS * 2);
    unsigned char* hs8 = (unsigned char*)alloc((size_t)NNODES * 256);
    unsigned short* gs = (unsigned short*)alloc((size_t)NNODES * 32 * 2);
    unsigned short* hcat = (unsigned short*)alloc((size_t)NNODES * 256 * 2);
    // binned arrays alias hcat (dead before agg12 writes hcat); 19.4MB <= 25.6MB
    unsigned int* binned1 = (unsigned int*)hcat;
    unsigned int* binned2 = binned1 + E1;

    hist2_kernel<<<nb1 + nb2, 256, 0, stream>>>(dst1, E1, nb1, hist1, dst2, E2, nb2, hist2);
    scanrow2_kernel<<<NBINS * 2, 256, 0, stream>>>(hist1, nb1, bs1, hist2, nb2, bs2);
    scanbs_kernel<<<2, 256, 0, stream>>>(bs1, bs2);
    scatter2_kernel<<<nb1 + nb2, 256, 0, stream>>>(src1, dst1, E1, nb1, hist1, bs1, binned1,
                                                   src2, dst2, E2, nb2, hist2, bs2, binned2);
    binfill2_kernel<<<NBINS * 2, 256, 0, stream>>>(binned1, bs1, rowptr1, dinv1, col1, E1,
                                                   binned2, bs2, rowptr2, dinv2, col2, E2);

    convW_kernel<<<DIM + 32, 256, 0, stream>>>(W1, W2, W3, Wt2, Wt3);
    gemm12_mfma_kernel<<<(NNODES + 63) / 64, 256, 0, stream>>>(x, Wt2, dinv1, dinv2, hs8);
    agg12_kernel<<<(AGG_WAVES_G1 + AGG_WAVES_G2) / 4, 256, 0, stream>>>(
        hs8, rowptr1, col1, rowptr2, col2, dinv1, dinv2, b1, b2, E1, E2, hcat);
    gemm3_mfma_kernel<<<(NNODES + 255) / 256, 256, 0, stream>>>(hcat, Wt3, dinv1, gs);
    agg3_kernel<<<A3_WAVES / 4, 256, 0, stream>>>(gs, rowptr1, col1, dinv1, b3, out, E1);
}